// Round 6
// baseline (1682.231 us; speedup 1.0000x reference)
//
#include <hip/hip_runtime.h>
#include <math.h>

#define N_V 3072
#define D_E 512
#define EDGE_CAP 128
constexpr float LRELU_ALPHA = 0.2f;
constexpr float NEG_INF_F = -9e15f;

typedef __attribute__((ext_vector_type(8))) short bf16x8;
typedef __attribute__((ext_vector_type(4))) float f32x4;
typedef __attribute__((ext_vector_type(4))) unsigned short ushort4v;
typedef __attribute__((ext_vector_type(2))) unsigned short ushort2v;

__device__ inline unsigned short f2bf(float f) {
    union { float f; unsigned int u; } x; x.f = f;
    unsigned int r = x.u + 0x7fffu + ((x.u >> 16) & 1u);
    return (unsigned short)(r >> 16);
}
__device__ inline float bf2f(unsigned short b) {
    union { unsigned int u; float f; } x; x.u = ((unsigned int)b) << 16;
    return x.f;
}

// XCD-aware bijective swizzle of the (bx,by) plane; nwg %8==0 for all grids.
__device__ inline void xcd_swizzle(int& bx, int& by) {
    int gx = gridDim.x, nwg = gx * gridDim.y;
    int flat = by * gx + bx;
    int q = nwg >> 3;
    int swz = (flat & 7) * q + (flat >> 3);
    bx = swz % gx; by = swz / gx;
}

// ---------------------------------------------------------------------------
// bf16 MFMA GEMM (materialized A): C = A @ BT^T.
// EPI 2: relu(acc + addv + bias) -> Cf (f32) and C0 (bf16).
// EPI 4: col<512 row-major bf16 C0; col>=512 transposed bf16 C1 [(col-512)][M].
// ---------------------------------------------------------------------------
template<int EPI>
__global__ __launch_bounds__(256) void gemm_bf16(
    const unsigned short* __restrict__ A,
    const unsigned short* __restrict__ BT,
    int M, int N, int K,
    unsigned short* __restrict__ C0, int ldc0,
    unsigned short* __restrict__ C1,
    const float* __restrict__ addv,
    const float* __restrict__ bias,
    float* __restrict__ Cf)
{
    constexpr int BM = 128, BN = 64, BK = 64;
    __shared__ unsigned short As[BM * BK];
    __shared__ unsigned short Bs[BN * BK];
    const int tid  = threadIdx.x;
    int bxi = blockIdx.x, byi = blockIdx.y;
    xcd_swizzle(bxi, byi);
    const int bm   = byi * BM, bn = bxi * BN;
    const int lane = tid & 63, wid = tid >> 6;
    const int wr   = wid >> 1, wc = wid & 1;
    const int lr   = lane & 15, lk = lane >> 4;

    f32x4 acc[4][2];
    #pragma unroll
    for (int i = 0; i < 4; ++i)
        #pragma unroll
        for (int j = 0; j < 2; ++j)
            acc[i][j] = (f32x4)(0.f);

    auto asp = (__attribute__((address_space(3))) unsigned short*)As;
    auto bsp = (__attribute__((address_space(3))) unsigned short*)Bs;

    for (int k0 = 0; k0 < K; k0 += BK) {
        #pragma unroll
        for (int l = 0; l < 4; ++l) {
            int li = l * 256 + tid;
            int row = li >> 3, slot = li & 7;
            int gs = slot ^ (row & 7);
            __builtin_amdgcn_global_load_lds(
                (const __attribute__((address_space(1))) void*)(A + (size_t)(bm + row) * K + k0 + gs * 8),
                (__attribute__((address_space(3))) void*)(asp + li * 8), 16, 0, 0);
        }
        #pragma unroll
        for (int l = 0; l < 2; ++l) {
            int li = l * 256 + tid;
            int row = li >> 3, slot = li & 7;
            int gs = slot ^ (row & 7);
            __builtin_amdgcn_global_load_lds(
                (const __attribute__((address_space(1))) void*)(BT + (size_t)(bn + row) * K + k0 + gs * 8),
                (__attribute__((address_space(3))) void*)(bsp + li * 8), 16, 0, 0);
        }
        __syncthreads();

        #pragma unroll
        for (int ks = 0; ks < 2; ++ks) {
            bf16x8 af[4], bfr[2];
            #pragma unroll
            for (int fm = 0; fm < 4; ++fm) {
                int row = wr * 64 + fm * 16 + lr;
                int sl = (ks * 4 + lk) ^ (row & 7);
                af[fm] = *(const bf16x8*)(As + row * BK + sl * 8);
            }
            #pragma unroll
            for (int fn = 0; fn < 2; ++fn) {
                int col = wc * 32 + fn * 16 + lr;
                int sl = (ks * 4 + lk) ^ (col & 7);
                bfr[fn] = *(const bf16x8*)(Bs + col * BK + sl * 8);
            }
            #pragma unroll
            for (int fm = 0; fm < 4; ++fm)
                #pragma unroll
                for (int fn = 0; fn < 2; ++fn)
                    acc[fm][fn] = __builtin_amdgcn_mfma_f32_16x16x32_bf16(
                        af[fm], bfr[fn], acc[fm][fn], 0, 0, 0);
        }
        __syncthreads();
    }

    #pragma unroll
    for (int fm = 0; fm < 4; ++fm) {
        #pragma unroll
        for (int fn = 0; fn < 2; ++fn) {
            int row0 = bm + wr * 64 + fm * 16 + lk * 4;
            int col  = bn + wc * 32 + fn * 16 + lr;
            f32x4 v = acc[fm][fn];
            if (EPI == 2) {
                #pragma unroll
                for (int r = 0; r < 4; ++r) {
                    float x = v[r] + addv[(size_t)(row0 + r) * N + col] + bias[col];
                    x = x > 0.f ? x : 0.f;
                    Cf[(size_t)(row0 + r) * N + col] = x;
                    C0[(size_t)(row0 + r) * ldc0 + col] = f2bf(x);
                }
            } else { // EPI 4
                if (col < 512) {
                    #pragma unroll
                    for (int r = 0; r < 4; ++r)
                        C0[(size_t)(row0 + r) * ldc0 + col] = f2bf(v[r]);
                } else {
                    ushort4v p;
                    p.x = f2bf(v[0]); p.y = f2bf(v[1]);
                    p.z = f2bf(v[2]); p.w = f2bf(v[3]);
                    *(ushort4v*)(C1 + (size_t)(col - 512) * M + row0) = p;
                }
            }
        }
    }
}

// ---------------------------------------------------------------------------
// Fused nn-attention GEMM: C[i,dim] = sum_k att(i,k) * Wh_nn[k,dim], where
// att(i,k) = (s_i+d_k>0 ? R1[i]*ed1[k] : R0[i]*ed0[k]), zeroed on neighbors
// and self.  A-tile is GENERATED in registers (never materialized).
// BM=128, BN=128, BK=64, split-K via blockIdx.z, fp32 partials.
// ---------------------------------------------------------------------------
template<int SPLITK>
__global__ __launch_bounds__(256) void gemm_nn(
    const unsigned short* __restrict__ BT,   // WhTnn [512][3072] bf16
    const float* __restrict__ dvec,
    const float* __restrict__ ed1v, const float* __restrict__ ed0v,
    const float* __restrict__ svec,
    const float* __restrict__ R1v, const float* __restrict__ R0v,
    const unsigned int* __restrict__ bitmask,
    float* __restrict__ Cp)                  // [SPLITK][N_V][D_E]
{
    constexpr int BM = 128, BN = 128, BK = 64;
    __shared__ unsigned short Bs[BN * BK];   // 16 KB
    __shared__ float dsh[BK], e1sh[BK], e0sh[BK];
    const int tid = threadIdx.x;
    int bxi = blockIdx.x, byi = blockIdx.y;
    xcd_swizzle(bxi, byi);
    const int bm = byi * BM, bn = bxi * BN;
    const int K  = N_V;
    const int kh = K / SPLITK;
    const int kbeg = blockIdx.z * kh, kend = kbeg + kh;
    const int lane = tid & 63, wid = tid >> 6;
    const int wr = wid >> 1, wc = wid & 1;
    const int lr = lane & 15, lk = lane >> 4;

    int   rows[4];
    float sR[4], r1R[4], r0R[4];
    #pragma unroll
    for (int fm = 0; fm < 4; ++fm) {
        rows[fm] = bm + wr * 64 + fm * 16 + lr;
        sR[fm]  = svec[rows[fm]];
        r1R[fm] = R1v[rows[fm]];
        r0R[fm] = R0v[rows[fm]];
    }

    f32x4 acc[4][4];
    #pragma unroll
    for (int i = 0; i < 4; ++i)
        #pragma unroll
        for (int j = 0; j < 4; ++j)
            acc[i][j] = (f32x4)(0.f);

    auto bsp = (__attribute__((address_space(3))) unsigned short*)Bs;

    for (int k0 = kbeg; k0 < kend; k0 += BK) {
        #pragma unroll
        for (int l = 0; l < 4; ++l) {
            int li = l * 256 + tid;
            int row = li >> 3, slot = li & 7;
            int gs = slot ^ (row & 7);
            __builtin_amdgcn_global_load_lds(
                (const __attribute__((address_space(1))) void*)(BT + (size_t)(bn + row) * K + k0 + gs * 8),
                (__attribute__((address_space(3))) void*)(bsp + li * 8), 16, 0, 0);
        }
        if (tid < 64)        dsh[tid]        = dvec[k0 + tid];
        else if (tid < 128)  e1sh[tid - 64]  = ed1v[k0 + tid - 64];
        else if (tid < 192)  e0sh[tid - 128] = ed0v[k0 + tid - 128];
        __syncthreads();

        #pragma unroll
        for (int ks = 0; ks < 2; ++ks) {
            const int kbl = ks * 32 + lk * 8;     // local k in [0,64)
            const int kg  = k0 + kbl;             // global k (multiple of 8)
            bf16x8 af[4];
            #pragma unroll
            for (int fm = 0; fm < 4; ++fm) {
                unsigned int word = bitmask[(size_t)rows[fm] * 96 + (kg >> 5)];
                int rel = rows[fm] - (kg & ~31);
                if ((unsigned)rel < 32u) word |= (1u << rel);   // self
                unsigned int bits = word >> (lk * 8);
                #pragma unroll
                for (int e = 0; e < 8; ++e) {
                    float dk = dsh[kbl + e];
                    bool pos = (sR[fm] + dk) > 0.f;
                    float v = pos ? r1R[fm] * e1sh[kbl + e]
                                  : r0R[fm] * e0sh[kbl + e];
                    if ((bits >> e) & 1u) v = 0.f;
                    af[fm][e] = (short)f2bf(v);
                }
            }
            bf16x8 bfr[4];
            #pragma unroll
            for (int fn = 0; fn < 4; ++fn) {
                int col = wc * 64 + fn * 16 + lr;
                int sl = (ks * 4 + lk) ^ (col & 7);
                bfr[fn] = *(const bf16x8*)(Bs + col * BK + sl * 8);
            }
            #pragma unroll
            for (int fm = 0; fm < 4; ++fm)
                #pragma unroll
                for (int fn = 0; fn < 4; ++fn)
                    acc[fm][fn] = __builtin_amdgcn_mfma_f32_16x16x32_bf16(
                        af[fm], bfr[fn], acc[fm][fn], 0, 0, 0);
        }
        __syncthreads();
    }

    float* Cz = Cp + (size_t)blockIdx.z * N_V * D_E;
    #pragma unroll
    for (int fm = 0; fm < 4; ++fm) {
        #pragma unroll
        for (int fn = 0; fn < 4; ++fn) {
            int row0 = bm + wr * 64 + fm * 16 + lk * 4;
            int col  = bn + wc * 64 + fn * 16 + lr;
            #pragma unroll
            for (int r = 0; r < 4; ++r)
                Cz[(size_t)(row0 + r) * D_E + col] = acc[fm][fn][r];
        }
    }
}

// Combine 4 split-K partials + ELU -> bf16 into cat[:,512:1024].
__global__ __launch_bounds__(256) void elu_combine4(
    const float* __restrict__ Cp, unsigned short* __restrict__ cat)
{
    int idx = blockIdx.x * 256 + threadIdx.x;   // 4-elem chunk
    const size_t S = (size_t)N_V * D_E;
    float4 a = ((const float4*)Cp)[idx];
    float4 b = ((const float4*)(Cp + S))[idx];
    float4 c = ((const float4*)(Cp + 2 * S))[idx];
    float4 d = ((const float4*)(Cp + 3 * S))[idx];
    int r = idx >> 7;
    int cc = (idx & 127) * 4;
    float v[4] = { a.x + b.x + c.x + d.x, a.y + b.y + c.y + d.y,
                   a.z + b.z + c.z + d.z, a.w + b.w + c.w + d.w };
    ushort4v o;
    #pragma unroll
    for (int q = 0; q < 4; ++q) {
        float x = v[q];
        x = x > 0.f ? x : (expf(x) - 1.f);
        ((unsigned short*)&o)[q] = f2bf(x);
    }
    *(ushort4v*)(cat + (size_t)r * (2 * D_E) + D_E + cc) = o;
}

// ---------------------------------------------------------------------------
// top-2 of d + ed1/ed0 tables, single block.
// topbuf: [dmax, d2max, bitcast(argmax)]
// ---------------------------------------------------------------------------
__global__ __launch_bounds__(256) void top2_ed(
    const float* __restrict__ d, float* __restrict__ topbuf,
    float* __restrict__ ed1, float* __restrict__ ed0)
{
    const int t = threadIdx.x;
    float m1 = -3.4e38f, m2 = -3.4e38f; int a1 = -1;
    for (int it = 0; it < 12; ++it) {
        int j = t + it * 256;
        float v = d[j];
        if (v > m1) { m2 = m1; m1 = v; a1 = j; }
        else if (v > m2) m2 = v;
    }
    __shared__ float m1s[256], m2s[256];
    __shared__ int a1s[256];
    m1s[t] = m1; m2s[t] = m2; a1s[t] = a1;
    __syncthreads();
    for (int o = 128; o; o >>= 1) {
        if (t < o) {
            float bm1 = m1s[t + o], bm2 = m2s[t + o]; int ba1 = a1s[t + o];
            if (bm1 > m1s[t]) {
                m2s[t] = fmaxf(m1s[t], bm2);
                m1s[t] = bm1; a1s[t] = ba1;
            } else {
                m2s[t] = fmaxf(m2s[t], bm1);
            }
        }
        __syncthreads();
    }
    float dmax = m1s[0];
    if (t == 0) {
        topbuf[0] = dmax; topbuf[1] = m2s[0];
        topbuf[2] = __int_as_float(a1s[0]);
    }
    for (int it = 0; it < 12; ++it) {
        int j = t + it * 256;
        float x = d[j] - dmax;
        ed1[j] = expf(x);
        ed0[j] = expf(0.2f * x);
    }
}

// ---------------------------------------------------------------------------
// Per-row Z and combined row factors R1=r1/Z, R0=r0/Z.  One wave per row.
// Z_i = r1*(S1 - C1) + r0*(S0 - C0); S over all j, C over neighbors+self.
// ---------------------------------------------------------------------------
__global__ __launch_bounds__(256) void nn_zrow(
    const float* __restrict__ d, const float* __restrict__ ed1,
    const float* __restrict__ ed0, const float* __restrict__ s,
    const int* __restrict__ edges, const int* __restrict__ deg,
    const float* __restrict__ topbuf,
    float* __restrict__ R1, float* __restrict__ R0)
{
    const int wave = threadIdx.x >> 6, lane = threadIdx.x & 63;
    const int i = blockIdx.x * 4 + wave;
    const float si = s[i];
    float S1 = 0.f, S0 = 0.f;
    #pragma unroll
    for (int it = 0; it < 48; ++it) {
        int j = lane + it * 64;
        float dj = d[j];
        bool pos = (si + dj) > 0.f;
        S1 += pos ? ed1[j] : 0.f;
        S0 += pos ? 0.f : ed0[j];
    }
    float C1 = 0.f, C0 = 0.f;
    const int cnt = deg[i];
    for (int e = lane; e < cnt; e += 64) {
        int j = edges[(size_t)i * EDGE_CAP + e];
        float dj = d[j];
        bool pos = (si + dj) > 0.f;
        C1 += pos ? ed1[j] : 0.f;
        C0 += pos ? 0.f : ed0[j];
    }
    if (lane == 63) {     // self term
        float dj = d[i];
        bool pos = (si + dj) > 0.f;
        C1 += pos ? ed1[i] : 0.f;
        C0 += pos ? 0.f : ed0[i];
    }
    #pragma unroll
    for (int off = 32; off; off >>= 1) {
        S1 += __shfl_down(S1, off); S0 += __shfl_down(S0, off);
        C1 += __shfl_down(C1, off); C0 += __shfl_down(C0, off);
    }
    if (lane == 0) {
        float dmax = topbuf[0], d2max = topbuf[1];
        int amax = __float_as_int(topbuf[2]);
        float dmx = (i == amax) ? d2max : dmax;
        float x = si + dmx;
        float m = x > 0.f ? x : LRELU_ALPHA * x;
        float r1 = expf(si + dmax - m);
        float r0 = expf(LRELU_ALPHA * (si + dmax) - m);
        float Z = r1 * (S1 - C1) + r0 * (S0 - C0);
        Z = fmaxf(Z, 1e-35f);
        R1[i] = r1 / Z; R0[i] = r0 / Z;
    }
}

// ---------------------------------------------------------------------------
// WT[n][k] = bf16(W[k][n]) ; flat bf16 convert
// ---------------------------------------------------------------------------
__global__ __launch_bounds__(256) void convT_f32_bf16(
    const float* __restrict__ W, unsigned short* __restrict__ WT, int K, int Nw)
{
    int k = blockIdx.x * 256 + threadIdx.x;
    int n = blockIdx.y;
    if (k < K) WT[(size_t)n * K + k] = f2bf(W[(size_t)k * Nw + n]);
}

__global__ __launch_bounds__(256) void conv_bf16(
    const float* __restrict__ X, unsigned short* __restrict__ Y, int n)
{
    int i = blockIdx.x * 256 + threadIdx.x;
    if (i < n) Y[i] = f2bf(X[i]);
}

// ---------------------------------------------------------------------------
// One-time: packed bitmask + deterministic per-row edge list.
// ---------------------------------------------------------------------------
__global__ __launch_bounds__(256) void build_graph(
    const float* __restrict__ adj, int* __restrict__ edges,
    int* __restrict__ deg, unsigned int* __restrict__ bitmask)
{
    const int i = blockIdx.x, t = threadIdx.x;
    __shared__ int cnts[256];
    unsigned int word = 0;
    int c = 0;
    if (t < 96) {
        #pragma unroll
        for (int b = 0; b < 32; ++b) {
            int j = t * 32 + b;
            if (adj[(size_t)i * N_V + j] > 0.f) { word |= (1u << b); ++c; }
        }
    }
    cnts[t] = c;
    __syncthreads();
    for (int o = 1; o < 256; o <<= 1) {
        int add = (t >= o) ? cnts[t - o] : 0;
        __syncthreads();
        cnts[t] += add;
        __syncthreads();
    }
    int base = cnts[t] - c;
    if (t < 96) {
        int k = 0;
        #pragma unroll
        for (int b = 0; b < 32; ++b) {
            if ((word >> b) & 1u) {
                int pos = base + k;
                if (pos < EDGE_CAP) edges[(size_t)i * EDGE_CAP + pos] = t * 32 + b;
                ++k;
            }
        }
        bitmask[(size_t)i * 96 + t] = word;
    }
    if (t == 0) deg[i] = cnts[255] < EDGE_CAP ? cnts[255] : EDGE_CAP;
}

// ---------------------------------------------------------------------------
// One-time: wv[0..5] = {W_n@as_n, W_n@ad_n, W_nn@as_nn, W_nn@ad_nn, W_g@as_g, W_g@ad_g}
// ---------------------------------------------------------------------------
__global__ __launch_bounds__(256) void matvec6(
    const float* __restrict__ W_n, const float* __restrict__ W_nn,
    const float* __restrict__ W_g,
    const float* __restrict__ as_n, const float* __restrict__ ad_n,
    const float* __restrict__ as_nn, const float* __restrict__ ad_nn,
    const float* __restrict__ as_g, const float* __restrict__ ad_g,
    float* __restrict__ wv)
{
    const int wave = threadIdx.x >> 6, lane = threadIdx.x & 63;
    const int r = blockIdx.x * 4 + wave;
    float a0 = 0, a1 = 0, a2 = 0, a3 = 0, a4 = 0, a5 = 0;
    #pragma unroll
    for (int k = 0; k < 8; ++k) {
        int c = lane + k * 64;
        float wn = W_n[(size_t)r * D_E + c];
        float wm = W_nn[(size_t)r * D_E + c];
        float wg = W_g[(size_t)r * D_E + c];
        a0 = fmaf(wn, as_n[c], a0);  a1 = fmaf(wn, ad_n[c], a1);
        a2 = fmaf(wm, as_nn[c], a2); a3 = fmaf(wm, ad_nn[c], a3);
        a4 = fmaf(wg, as_g[c], a4);  a5 = fmaf(wg, ad_g[c], a5);
    }
    #pragma unroll
    for (int off = 32; off; off >>= 1) {
        a0 += __shfl_down(a0, off); a1 += __shfl_down(a1, off);
        a2 += __shfl_down(a2, off); a3 += __shfl_down(a3, off);
        a4 += __shfl_down(a4, off); a5 += __shfl_down(a5, off);
    }
    if (lane == 0) {
        wv[0 * D_E + r] = a0; wv[1 * D_E + r] = a1;
        wv[2 * D_E + r] = a2; wv[3 * D_E + r] = a3;
        wv[4 * D_E + r] = a4; wv[5 * D_E + r] = a5;
    }
}

// ---------------------------------------------------------------------------
// outs[v][i] = emb_bf16[i,:] . wv[v]
// ---------------------------------------------------------------------------
template<int NV>
__global__ __launch_bounds__(256) void sd_dots(
    const unsigned short* __restrict__ emb, const float* __restrict__ wv,
    float* __restrict__ outs)
{
    const int wave = threadIdx.x >> 6, lane = threadIdx.x & 63;
    const int i = blockIdx.x * 4 + wave;
    float acc[NV];
    #pragma unroll
    for (int v = 0; v < NV; ++v) acc[v] = 0.f;
    #pragma unroll
    for (int k = 0; k < 8; ++k) {
        int c = lane + k * 64;
        float x = bf2f(emb[(size_t)i * D_E + c]);
        #pragma unroll
        for (int v = 0; v < NV; ++v) acc[v] = fmaf(x, wv[v * D_E + c], acc[v]);
    }
    #pragma unroll
    for (int off = 32; off; off >>= 1)
        #pragma unroll
        for (int v = 0; v < NV; ++v) acc[v] += __shfl_down(acc[v], off);
    if (lane == 0)
        #pragma unroll
        for (int v = 0; v < NV; ++v) outs[v * N_V + i] = acc[v];
}

// ---------------------------------------------------------------------------
// Sparse neighbor branch: softmax over edges + weighted sum of Whn + ELU.
// ---------------------------------------------------------------------------
__global__ __launch_bounds__(256) void neigh_gather(
    const int* __restrict__ edges, const int* __restrict__ deg,
    const float* __restrict__ s, const float* __restrict__ dvec,
    const unsigned short* __restrict__ Whn, unsigned short* __restrict__ cat)
{
    const int i = blockIdx.x, t = threadIdx.x;
    const int cnt = deg[i];
    __shared__ float p[EDGE_CAP];
    __shared__ int lst[EDGE_CAP];
    __shared__ float red[256];
    float ev = -3.4e38f;
    if (t < cnt) {
        int j = edges[(size_t)i * EDGE_CAP + t];
        lst[t] = j;
        float x = s[i] + dvec[j];
        x = x > 0.f ? x : LRELU_ALPHA * x;
        p[t] = x;
        ev = x;
    }
    red[t] = ev; __syncthreads();
    for (int o = 128; o; o >>= 1) {
        if (t < o) red[t] = fmaxf(red[t], red[t + o]);
        __syncthreads();
    }
    float m = red[0]; __syncthreads();
    float pe = 0.f;
    if (t < cnt) { pe = expf(p[t] - m); p[t] = pe; }
    red[t] = pe; __syncthreads();
    for (int o = 128; o; o >>= 1) {
        if (t < o) red[t] += red[t + o];
        __syncthreads();
    }
    const float zinv = 1.f / red[0];
    float a0 = 0.f, a1 = 0.f;
    for (int e = 0; e < cnt; ++e) {
        int j = lst[e];
        float w = p[e] * zinv;
        ushort2v h = *(const ushort2v*)(Whn + (size_t)j * D_E + t * 2);
        a0 = fmaf(w, bf2f(h.x), a0);
        a1 = fmaf(w, bf2f(h.y), a1);
    }
    a0 = a0 > 0.f ? a0 : (expf(a0) - 1.f);
    a1 = a1 > 0.f ? a1 : (expf(a1) - 1.f);
    ushort2v o2; o2.x = f2bf(a0); o2.y = f2bf(a1);
    *(ushort2v*)(cat + (size_t)i * (2 * D_E) + t * 2) = o2;
}

// sq[i] = sum(emb[i,:]^2), fp32
__global__ __launch_bounds__(256) void rowsumsq(
    const float* __restrict__ emb, float* __restrict__ sq)
{
    const int wave = threadIdx.x >> 6, lane = threadIdx.x & 63;
    const int row = blockIdx.x * 4 + wave;
    const float* w = emb + (size_t)row * D_E;
    float ss = 0.f;
    #pragma unroll
    for (int k = 0; k < 8; ++k) {
        float x = w[lane + k * 64];
        ss = fmaf(x, x, ss);
    }
    #pragma unroll
    for (int off = 32; off; off >>= 1) ss += __shfl_down(ss, off);
    if (lane == 0) sq[row] = ss;
}

// ---------------------------------------------------------------------------
// Edge-list embedding loss, fp32, 16-lane groups (one edge per group-step).
// ---------------------------------------------------------------------------
__global__ __launch_bounds__(256) void edge_loss3(
    const int* __restrict__ edges, const int* __restrict__ deg,
    const float* __restrict__ emb, const float* __restrict__ sq,
    float* __restrict__ accum)
{
    __shared__ float eish[D_E];
    __shared__ float gsum[16];
    const int i = blockIdx.x, t = threadIdx.x;
    if (t < 128) ((float4*)eish)[t] = ((const float4*)(emb + (size_t)i * D_E))[t];
    __syncthreads();
    const int g = t >> 4, l = t & 15;
    const int cnt = deg[i];
    float sum = 0.f;
    for (int e = g; e < cnt; e += 16) {
        int j = edges[(size_t)i * EDGE_CAP + e];
        float dot = 0.f;
        #pragma unroll
        for (int q = 0; q < 8; ++q) {
            int off = q * 64 + l * 4;
            float4 a = *(const float4*)(eish + off);
            float4 b = *(const float4*)(emb + (size_t)j * D_E + off);
            dot += a.x * b.x + a.y * b.y + a.z * b.z + a.w * b.w;
        }
        #pragma unroll
        for (int msk = 1; msk < 16; msk <<= 1) dot += __shfl_xor(dot, msk);
        if (l == 0) {
            float d2 = sq[i] + sq[j] - 2.f * dot;
            sum += sqrtf(fmaxf(d2, 1e-12f));
        }
    }
    if (l == 0) gsum[g] = sum;
    __syncthreads();
    if (t == 0) {
        float tot = 0.f;
        #pragma unroll
        for (int k = 0; k < 16; ++k) tot += gsum[k];
        atomicAdd(accum, -tot);
    }
}

// ---------------------------------------------------------------------------
// Glimpse confidence via bitmask (keep = bit): conf_i = 1/Z_i.
// ---------------------------------------------------------------------------
__global__ __launch_bounds__(256) void conf_kernel(
    const unsigned int* __restrict__ bitmask, const float* __restrict__ s,
    const float* __restrict__ dvec, float* __restrict__ accum)
{
    const int i = blockIdx.x, t = threadIdx.x;
    __shared__ unsigned int mrow[96];
    __shared__ float red[256];
    if (t < 96) mrow[t] = bitmask[(size_t)i * 96 + t];
    __syncthreads();
    const float si = s[i];
    const float4* dv4 = (const float4*)dvec;
    float e[3][4];
    float mloc = -3.4e38f;
    #pragma unroll
    for (int l = 0; l < 3; ++l) {
        int jv = t + l * 256;
        float4 d = dv4[jv];
        int j0 = jv * 4;
        unsigned int w = mrow[j0 >> 5];
        #pragma unroll
        for (int c = 0; c < 4; ++c) {
            int j = j0 + c;
            bool keep = ((w >> (j & 31)) & 1u) != 0u;
            float x = si + ((const float*)&d)[c];
            x = x > 0.f ? x : LRELU_ALPHA * x;
            e[l][c] = keep ? x : NEG_INF_F;
            mloc = fmaxf(mloc, e[l][c]);
        }
    }
    red[t] = mloc; __syncthreads();
    for (int o = 128; o; o >>= 1) {
        if (t < o) red[t] = fmaxf(red[t], red[t + o]);
        __syncthreads();
    }
    float m = red[0]; __syncthreads();
    float zloc = 0.f;
    #pragma unroll
    for (int l = 0; l < 3; ++l)
        #pragma unroll
        for (int c = 0; c < 4; ++c) zloc += expf(e[l][c] - m);
    red[t] = zloc; __syncthreads();
    for (int o = 128; o; o >>= 1) {
        if (t < o) red[t] += red[t + o];
        __syncthreads();
    }
    if (t == 0) atomicAdd(accum, logf(1.f / red[0] + 1e-8f));
}

__global__ void finalize(const float* __restrict__ accum, float* __restrict__ out)
{
    float loss = accum[0];
    out[0] = fmaxf(loss + 400.f, 0.f);
    out[1] = loss;
    out[2] = accum[1] / (float)N_V - logf(1e-8f);
}

// ---------------------------------------------------------------------------
extern "C" void kernel_launch(void* const* d_in, const int* in_sizes, int n_in,
                              void* d_out, int out_size, void* d_ws, size_t ws_size,
                              hipStream_t stream) {
    const float* emb_in   = (const float*)d_in[0];
    const float* adj      = (const float*)d_in[1];
    const float* W_n      = (const float*)d_in[2];
    const float* a_src_n  = (const float*)d_in[3];
    const float* a_dst_n  = (const float*)d_in[4];
    const float* W_nn     = (const float*)d_in[5];
    const float* a_src_nn = (const float*)d_in[6];
    const float* a_dst_nn = (const float*)d_in[7];
    const float* W_u      = (const float*)d_in[8];
    const float* b_u      = (const float*)d_in[9];
    const float* W_g      = (const float*)d_in[10];
    const float* a_src_g  = (const float*)d_in[11];
    const float* a_dst_g  = (const float*)d_in[12];
    float* out = (float*)d_out;

    char* p = (char*)d_ws;
    auto alloc = [&](size_t bytes) { char* r = p; p += (bytes + 255) & ~(size_t)255; return r; };

    float*          Cp      = (float*)alloc((size_t)4 * N_V * D_E * 4);
    unsigned short* Whn     = (unsigned short*)alloc((size_t)N_V * D_E * 2);
    unsigned short* WhTnn   = (unsigned short*)alloc((size_t)D_E * N_V * 2);
    unsigned short* cat_bf  = (unsigned short*)alloc((size_t)N_V * 2 * D_E * 2);
    float*          embf[2] = { (float*)alloc((size_t)N_V * D_E * 4),
                                (float*)alloc((size_t)N_V * D_E * 4) };
    unsigned short* embb[2] = { (unsigned short*)alloc((size_t)N_V * D_E * 2),
                                (unsigned short*)alloc((size_t)N_V * D_E * 2) };
    unsigned short* W2T     = (unsigned short*)alloc((size_t)(2 * D_E) * D_E * 2);
    unsigned short* WuT     = (unsigned short*)alloc((size_t)D_E * (2 * D_E) * 2);
    float*          wv      = (float*)alloc(6 * D_E * 4);
    float*          sd      = (float*)alloc(4 * N_V * 4);
    float*          sdg     = (float*)alloc(2 * N_V * 4);
    float*          sq      = (float*)alloc(N_V * 4);
    float*          ed1     = (float*)alloc(N_V * 4);
    float*          ed0     = (float*)alloc(N_V * 4);
    float*          R1      = (float*)alloc(N_V * 4);
    float*          R0      = (float*)alloc(N_V * 4);
    float*          topbuf  = (float*)alloc(4 * 4);
    int*            edges   = (int*)alloc((size_t)N_V * EDGE_CAP * 4);
    int*            deg     = (int*)alloc(N_V * 4);
    unsigned int*   bitmask = (unsigned int*)alloc((size_t)N_V * 96 * 4);
    float*          accum   = (float*)alloc(2 * 4);

    dim3 blk(256);

    // one-time prepass
    convT_f32_bf16<<<dim3(2, D_E), blk, 0, stream>>>(W_n, W2T, D_E, D_E);
    convT_f32_bf16<<<dim3(2, D_E), blk, 0, stream>>>(W_nn, W2T + (size_t)D_E * D_E, D_E, D_E);
    convT_f32_bf16<<<dim3(4, D_E), blk, 0, stream>>>(W_u, WuT, 2 * D_E, D_E);
    conv_bf16<<<(N_V * D_E) / 256, blk, 0, stream>>>(emb_in, embb[0], N_V * D_E);
    hipMemcpyAsync(embf[0], emb_in, (size_t)N_V * D_E * 4, hipMemcpyDeviceToDevice, stream);
    hipMemsetAsync(accum, 0, 2 * sizeof(float), stream);
    build_graph<<<N_V, blk, 0, stream>>>(adj, edges, deg, bitmask);
    matvec6<<<D_E / 4, blk, 0, stream>>>(W_n, W_nn, W_g, a_src_n, a_dst_n,
                                         a_src_nn, a_dst_nn, a_src_g, a_dst_g, wv);

    dim3 gW2(16, N_V / 128);            // fused Wh GEMM (N=1024)
    dim3 gG(8, N_V / 128);              // update GEMM (N=512)
    dim3 gNN(4, N_V / 128, 4);          // fused nn GEMM, split-K=4

    const float* d_nn = sd + 3 * N_V;
    const float* s_nn = sd + 2 * N_V;

    int cur = 0;
    for (int it = 0; it < 10; ++it) {
        int nxt = cur ^ 1;
        sd_dots<4><<<N_V / 4, blk, 0, stream>>>(embb[cur], wv, sd);
        gemm_bf16<4><<<gW2, blk, 0, stream>>>(embb[cur], W2T, N_V, 2 * D_E, D_E,
                                              Whn, D_E, WhTnn, nullptr, nullptr, nullptr);
        top2_ed<<<1, blk, 0, stream>>>(d_nn, topbuf, ed1, ed0);
        nn_zrow<<<N_V / 4, blk, 0, stream>>>(d_nn, ed1, ed0, s_nn,
                                             edges, deg, topbuf, R1, R0);
        neigh_gather<<<N_V, blk, 0, stream>>>(edges, deg, sd, sd + N_V, Whn, cat_bf);
        gemm_nn<4><<<gNN, blk, 0, stream>>>(WhTnn, d_nn, ed1, ed0, s_nn,
                                            R1, R0, bitmask, Cp);
        elu_combine4<<<(N_V * D_E) / (4 * 256), blk, 0, stream>>>(Cp, cat_bf);
        gemm_bf16<2><<<gG, blk, 0, stream>>>(cat_bf, WuT, N_V, D_E, 2 * D_E,
                                             embb[nxt], D_E, nullptr, embf[cur], b_u, embf[nxt]);
        cur = nxt;
    }

    // losses
    rowsumsq<<<N_V / 4, blk, 0, stream>>>(embf[cur], sq);
    edge_loss3<<<N_V, blk, 0, stream>>>(edges, deg, embf[cur], sq, accum);
    sd_dots<2><<<N_V / 4, blk, 0, stream>>>(embb[cur], wv + 4 * D_E, sdg);
    conf_kernel<<<N_V, blk, 0, stream>>>(bitmask, sdg, sdg + N_V, accum + 1);

    finalize<<<1, 1, 0, stream>>>(accum, out);
}

// Round 7
// 912.129 us; speedup vs baseline: 1.8443x; 1.8443x over previous
//
#include <hip/hip_runtime.h>
#include <math.h>

#define N_V 3072
#define D_E 512
#define EDGE_CAP 128
constexpr float LRELU_ALPHA = 0.2f;
constexpr float NEG_INF_F = -9e15f;

typedef __attribute__((ext_vector_type(8))) short bf16x8;
typedef __attribute__((ext_vector_type(4))) float f32x4;
typedef __attribute__((ext_vector_type(4))) unsigned short ushort4v;
typedef __attribute__((ext_vector_type(2))) unsigned short ushort2v;

__device__ inline unsigned short f2bf(float f) {
    union { float f; unsigned int u; } x; x.f = f;
    unsigned int r = x.u + 0x7fffu + ((x.u >> 16) & 1u);
    return (unsigned short)(r >> 16);
}
__device__ inline float bf2f(unsigned short b) {
    union { unsigned int u; float f; } x; x.u = ((unsigned int)b) << 16;
    return x.f;
}

// XCD-aware bijective swizzle of the (bx,by) plane; nwg %8==0 for all grids
// here (384/192/96-per-z-plane).
__device__ inline void xcd_swizzle(int& bx, int& by) {
    int gx = gridDim.x, nwg = gx * gridDim.y;
    int flat = by * gx + bx;
    int q = nwg >> 3;
    int swz = (flat & 7) * q + (flat >> 3);
    bx = swz % gx; by = swz / gx;
}

// ---------------------------------------------------------------------------
// bf16 MFMA GEMM: C[M,N] = A[M,K] @ B[K,N], B given TRANSPOSED (BT[N][K]).
// Tile 128x64, BK=64, 4 waves (2x2), wave tile 64x32, 16x16x32 MFMA.
// EPI 2: relu(acc + addv + bias) -> Cf (f32, ld=N) and C0 (bf16, ldc0).
// EPI 4: split: col<512 -> row-major bf16 C0 (ldc0=512);
//               col>=512 -> transposed bf16 C1 [(col-512)][M].
// ---------------------------------------------------------------------------
template<int EPI>
__global__ __launch_bounds__(256) void gemm_bf16(
    const unsigned short* __restrict__ A,   // [M][K] bf16
    const unsigned short* __restrict__ BT,  // [N][K] bf16
    int M, int N, int K,
    unsigned short* __restrict__ C0, int ldc0,
    unsigned short* __restrict__ C1,
    const float* __restrict__ addv,
    const float* __restrict__ bias,
    float* __restrict__ Cf)
{
    constexpr int BM = 128, BN = 64, BK = 64;
    __shared__ unsigned short As[BM * BK];
    __shared__ unsigned short Bs[BN * BK];
    const int tid  = threadIdx.x;
    int bxi = blockIdx.x, byi = blockIdx.y;
    xcd_swizzle(bxi, byi);
    const int bm   = byi * BM, bn = bxi * BN;
    const int lane = tid & 63, wid = tid >> 6;
    const int wr   = wid >> 1, wc = wid & 1;
    const int lr   = lane & 15, lk = lane >> 4;

    f32x4 acc[4][2];
    #pragma unroll
    for (int i = 0; i < 4; ++i)
        #pragma unroll
        for (int j = 0; j < 2; ++j)
            acc[i][j] = (f32x4)(0.f);

    auto asp = (__attribute__((address_space(3))) unsigned short*)As;
    auto bsp = (__attribute__((address_space(3))) unsigned short*)Bs;

    for (int k0 = 0; k0 < K; k0 += BK) {
        #pragma unroll
        for (int l = 0; l < 4; ++l) {
            int li = l * 256 + tid;
            int row = li >> 3, slot = li & 7;
            int gs = slot ^ (row & 7);
            __builtin_amdgcn_global_load_lds(
                (const __attribute__((address_space(1))) void*)(A + (size_t)(bm + row) * K + k0 + gs * 8),
                (__attribute__((address_space(3))) void*)(asp + li * 8), 16, 0, 0);
        }
        #pragma unroll
        for (int l = 0; l < 2; ++l) {
            int li = l * 256 + tid;
            int row = li >> 3, slot = li & 7;
            int gs = slot ^ (row & 7);
            __builtin_amdgcn_global_load_lds(
                (const __attribute__((address_space(1))) void*)(BT + (size_t)(bn + row) * K + k0 + gs * 8),
                (__attribute__((address_space(3))) void*)(bsp + li * 8), 16, 0, 0);
        }
        __syncthreads();

        #pragma unroll
        for (int ks = 0; ks < 2; ++ks) {
            bf16x8 af[4], bfr[2];
            #pragma unroll
            for (int fm = 0; fm < 4; ++fm) {
                int row = wr * 64 + fm * 16 + lr;
                int sl = (ks * 4 + lk) ^ (row & 7);
                af[fm] = *(const bf16x8*)(As + row * BK + sl * 8);
            }
            #pragma unroll
            for (int fn = 0; fn < 2; ++fn) {
                int col = wc * 32 + fn * 16 + lr;
                int sl = (ks * 4 + lk) ^ (col & 7);
                bfr[fn] = *(const bf16x8*)(Bs + col * BK + sl * 8);
            }
            #pragma unroll
            for (int fm = 0; fm < 4; ++fm)
                #pragma unroll
                for (int fn = 0; fn < 2; ++fn)
                    acc[fm][fn] = __builtin_amdgcn_mfma_f32_16x16x32_bf16(
                        af[fm], bfr[fn], acc[fm][fn], 0, 0, 0);
        }
        __syncthreads();
    }

    #pragma unroll
    for (int fm = 0; fm < 4; ++fm) {
        #pragma unroll
        for (int fn = 0; fn < 2; ++fn) {
            int row0 = bm + wr * 64 + fm * 16 + lk * 4;
            int col  = bn + wc * 32 + fn * 16 + lr;
            f32x4 v = acc[fm][fn];
            if (EPI == 2) {
                #pragma unroll
                for (int r = 0; r < 4; ++r) {
                    float x = v[r] + addv[(size_t)(row0 + r) * N + col] + bias[col];
                    x = x > 0.f ? x : 0.f;
                    Cf[(size_t)(row0 + r) * N + col] = x;
                    C0[(size_t)(row0 + r) * ldc0 + col] = f2bf(x);
                }
            } else { // EPI 4
                if (col < 512) {
                    #pragma unroll
                    for (int r = 0; r < 4; ++r)
                        C0[(size_t)(row0 + r) * ldc0 + col] = f2bf(v[r]);
                } else {
                    ushort4v p;
                    p.x = f2bf(v[0]); p.y = f2bf(v[1]);
                    p.z = f2bf(v[2]); p.w = f2bf(v[3]);
                    *(ushort4v*)(C1 + (size_t)(col - 512) * M + row0) = p;
                }
            }
        }
    }
}

// ---------------------------------------------------------------------------
// Split-K nn GEMM: 128x128 tile, BK=64, 4 waves (2x2), wave tile 64x64,
// 32 MFMA per K-step.  blockIdx.z selects K-quarter; fp32 partials.
// ---------------------------------------------------------------------------
template<int SPLITK>
__global__ __launch_bounds__(256) void gemm_bf16_sk(
    const unsigned short* __restrict__ A,
    const unsigned short* __restrict__ BT,
    int M, int N, int K,
    float* __restrict__ Cp)
{
    constexpr int BM = 128, BN = 128, BK = 64;
    __shared__ unsigned short As[BM * BK];
    __shared__ unsigned short Bs[BN * BK];
    const int tid  = threadIdx.x;
    int bxi = blockIdx.x, byi = blockIdx.y;
    xcd_swizzle(bxi, byi);
    const int bm   = byi * BM, bn = bxi * BN;
    const int kh   = K / SPLITK;
    const int kbeg = blockIdx.z * kh, kend = kbeg + kh;
    const int lane = tid & 63, wid = tid >> 6;
    const int wr   = wid >> 1, wc = wid & 1;
    const int lr   = lane & 15, lk = lane >> 4;

    f32x4 acc[4][4];
    #pragma unroll
    for (int i = 0; i < 4; ++i)
        #pragma unroll
        for (int j = 0; j < 4; ++j)
            acc[i][j] = (f32x4)(0.f);

    auto asp = (__attribute__((address_space(3))) unsigned short*)As;
    auto bsp = (__attribute__((address_space(3))) unsigned short*)Bs;

    for (int k0 = kbeg; k0 < kend; k0 += BK) {
        #pragma unroll
        for (int l = 0; l < 4; ++l) {
            int li = l * 256 + tid;
            int row = li >> 3, slot = li & 7;
            int gs = slot ^ (row & 7);
            __builtin_amdgcn_global_load_lds(
                (const __attribute__((address_space(1))) void*)(A + (size_t)(bm + row) * K + k0 + gs * 8),
                (__attribute__((address_space(3))) void*)(asp + li * 8), 16, 0, 0);
        }
        #pragma unroll
        for (int l = 0; l < 4; ++l) {
            int li = l * 256 + tid;
            int row = li >> 3, slot = li & 7;
            int gs = slot ^ (row & 7);
            __builtin_amdgcn_global_load_lds(
                (const __attribute__((address_space(1))) void*)(BT + (size_t)(bn + row) * K + k0 + gs * 8),
                (__attribute__((address_space(3))) void*)(bsp + li * 8), 16, 0, 0);
        }
        __syncthreads();

        #pragma unroll
        for (int ks = 0; ks < 2; ++ks) {
            bf16x8 af[4], bfr[4];
            #pragma unroll
            for (int fm = 0; fm < 4; ++fm) {
                int row = wr * 64 + fm * 16 + lr;
                int sl = (ks * 4 + lk) ^ (row & 7);
                af[fm] = *(const bf16x8*)(As + row * BK + sl * 8);
            }
            #pragma unroll
            for (int fn = 0; fn < 4; ++fn) {
                int col = wc * 64 + fn * 16 + lr;
                int sl = (ks * 4 + lk) ^ (col & 7);
                bfr[fn] = *(const bf16x8*)(Bs + col * BK + sl * 8);
            }
            #pragma unroll
            for (int fm = 0; fm < 4; ++fm)
                #pragma unroll
                for (int fn = 0; fn < 4; ++fn)
                    acc[fm][fn] = __builtin_amdgcn_mfma_f32_16x16x32_bf16(
                        af[fm], bfr[fn], acc[fm][fn], 0, 0, 0);
        }
        __syncthreads();
    }

    float* Cz = Cp + (size_t)blockIdx.z * M * N;
    #pragma unroll
    for (int fm = 0; fm < 4; ++fm) {
        #pragma unroll
        for (int fn = 0; fn < 4; ++fn) {
            int row0 = bm + wr * 64 + fm * 16 + lk * 4;
            int col  = bn + wc * 64 + fn * 16 + lr;
            #pragma unroll
            for (int r = 0; r < 4; ++r)
                Cz[(size_t)(row0 + r) * N + col] = acc[fm][fn][r];
        }
    }
}

// Combine 4 split-K partials + ELU -> bf16 into cat[:,512:1024].
__global__ __launch_bounds__(256) void elu_combine4(
    const float* __restrict__ Cp, unsigned short* __restrict__ cat)
{
    int idx = blockIdx.x * 256 + threadIdx.x;   // 4-elem chunk
    const size_t S = (size_t)N_V * D_E;
    float4 a = ((const float4*)Cp)[idx];
    float4 b = ((const float4*)(Cp + S))[idx];
    float4 c = ((const float4*)(Cp + 2 * S))[idx];
    float4 d = ((const float4*)(Cp + 3 * S))[idx];
    int r = idx >> 7;
    int cc = (idx & 127) * 4;
    float v[4] = { a.x + b.x + c.x + d.x, a.y + b.y + c.y + d.y,
                   a.z + b.z + c.z + d.z, a.w + b.w + c.w + d.w };
    ushort4v o;
    #pragma unroll
    for (int q = 0; q < 4; ++q) {
        float x = v[q];
        x = x > 0.f ? x : (expf(x) - 1.f);
        ((unsigned short*)&o)[q] = f2bf(x);
    }
    *(ushort4v*)(cat + (size_t)r * (2 * D_E) + D_E + cc) = o;
}

// ---------------------------------------------------------------------------
// WT[n][k] = bf16(W[k][n]) ; flat bf16 convert
// ---------------------------------------------------------------------------
__global__ __launch_bounds__(256) void convT_f32_bf16(
    const float* __restrict__ W, unsigned short* __restrict__ WT, int K, int Nw)
{
    int k = blockIdx.x * 256 + threadIdx.x;
    int n = blockIdx.y;
    if (k < K) WT[(size_t)n * K + k] = f2bf(W[(size_t)k * Nw + n]);
}

__global__ __launch_bounds__(256) void conv_bf16(
    const float* __restrict__ X, unsigned short* __restrict__ Y, int n)
{
    int i = blockIdx.x * 256 + threadIdx.x;
    if (i < n) Y[i] = f2bf(X[i]);
}

// ---------------------------------------------------------------------------
// One-time: packed bitmask + deterministic per-row edge list.
// ---------------------------------------------------------------------------
__global__ __launch_bounds__(256) void build_graph(
    const float* __restrict__ adj, int* __restrict__ edges,
    int* __restrict__ deg, unsigned int* __restrict__ bitmask)
{
    const int i = blockIdx.x, t = threadIdx.x;
    __shared__ int cnts[256];
    unsigned int word = 0;
    int c = 0;
    if (t < 96) {
        #pragma unroll
        for (int b = 0; b < 32; ++b) {
            int j = t * 32 + b;
            if (adj[(size_t)i * N_V + j] > 0.f) { word |= (1u << b); ++c; }
        }
    }
    cnts[t] = c;
    __syncthreads();
    for (int o = 1; o < 256; o <<= 1) {
        int add = (t >= o) ? cnts[t - o] : 0;
        __syncthreads();
        cnts[t] += add;
        __syncthreads();
    }
    int base = cnts[t] - c;
    if (t < 96) {
        int k = 0;
        #pragma unroll
        for (int b = 0; b < 32; ++b) {
            if ((word >> b) & 1u) {
                int pos = base + k;
                if (pos < EDGE_CAP) edges[(size_t)i * EDGE_CAP + pos] = t * 32 + b;
                ++k;
            }
        }
        bitmask[(size_t)i * 96 + t] = word;
    }
    if (t == 0) deg[i] = cnts[255] < EDGE_CAP ? cnts[255] : EDGE_CAP;
}

// ---------------------------------------------------------------------------
// One-time: wv[0..5] = {W_n@as_n, W_n@ad_n, W_nn@as_nn, W_nn@ad_nn, W_g@as_g, W_g@ad_g}
// ---------------------------------------------------------------------------
__global__ __launch_bounds__(256) void matvec6(
    const float* __restrict__ W_n, const float* __restrict__ W_nn,
    const float* __restrict__ W_g,
    const float* __restrict__ as_n, const float* __restrict__ ad_n,
    const float* __restrict__ as_nn, const float* __restrict__ ad_nn,
    const float* __restrict__ as_g, const float* __restrict__ ad_g,
    float* __restrict__ wv)
{
    const int wave = threadIdx.x >> 6, lane = threadIdx.x & 63;
    const int r = blockIdx.x * 4 + wave;
    float a0 = 0, a1 = 0, a2 = 0, a3 = 0, a4 = 0, a5 = 0;
    #pragma unroll
    for (int k = 0; k < 8; ++k) {
        int c = lane + k * 64;
        float wn = W_n[(size_t)r * D_E + c];
        float wm = W_nn[(size_t)r * D_E + c];
        float wg = W_g[(size_t)r * D_E + c];
        a0 = fmaf(wn, as_n[c], a0);  a1 = fmaf(wn, ad_n[c], a1);
        a2 = fmaf(wm, as_nn[c], a2); a3 = fmaf(wm, ad_nn[c], a3);
        a4 = fmaf(wg, as_g[c], a4);  a5 = fmaf(wg, ad_g[c], a5);
    }
    #pragma unroll
    for (int off = 32; off; off >>= 1) {
        a0 += __shfl_down(a0, off); a1 += __shfl_down(a1, off);
        a2 += __shfl_down(a2, off); a3 += __shfl_down(a3, off);
        a4 += __shfl_down(a4, off); a5 += __shfl_down(a5, off);
    }
    if (lane == 0) {
        wv[0 * D_E + r] = a0; wv[1 * D_E + r] = a1;
        wv[2 * D_E + r] = a2; wv[3 * D_E + r] = a3;
        wv[4 * D_E + r] = a4; wv[5 * D_E + r] = a5;
    }
}

// ---------------------------------------------------------------------------
// outs[v][i] = emb_bf16[i,:] . wv[v]
// ---------------------------------------------------------------------------
template<int NV>
__global__ __launch_bounds__(256) void sd_dots(
    const unsigned short* __restrict__ emb, const float* __restrict__ wv,
    float* __restrict__ outs)
{
    const int wave = threadIdx.x >> 6, lane = threadIdx.x & 63;
    const int i = blockIdx.x * 4 + wave;
    float acc[NV];
    #pragma unroll
    for (int v = 0; v < NV; ++v) acc[v] = 0.f;
    #pragma unroll
    for (int k = 0; k < 8; ++k) {
        int c = lane + k * 64;
        float x = bf2f(emb[(size_t)i * D_E + c]);
        #pragma unroll
        for (int v = 0; v < NV; ++v) acc[v] = fmaf(x, wv[v * D_E + c], acc[v]);
    }
    #pragma unroll
    for (int off = 32; off; off >>= 1)
        #pragma unroll
        for (int v = 0; v < NV; ++v) acc[v] += __shfl_down(acc[v], off);
    if (lane == 0)
        #pragma unroll
        for (int v = 0; v < NV; ++v) outs[v * N_V + i] = acc[v];
}

// ---------------------------------------------------------------------------
// Fused: blocks [0,N_V) run non-neighbor softmax (writes att bf16);
// blocks [N_V,2N_V) run the sparse neighbor gather (writes cat[:,0:512]).
// sd layout: s_n = sd, d_n = sd+N, s_nn = sd+2N, d_nn = sd+3N.
// ---------------------------------------------------------------------------
__global__ __launch_bounds__(256) void nn_sm_gather(
    const unsigned int* __restrict__ bitmask,
    const int* __restrict__ edges, const int* __restrict__ deg,
    const float* __restrict__ sd,
    const unsigned short* __restrict__ Whn,
    unsigned short* __restrict__ att, unsigned short* __restrict__ cat)
{
    const int t = threadIdx.x;
    __shared__ float red[256];
    if (blockIdx.x < N_V) {
        const int i = blockIdx.x;
        const float* s = sd + 2 * N_V;
        const float* dvec = sd + 3 * N_V;
        __shared__ unsigned int mrow[96];
        if (t < 96) mrow[t] = bitmask[(size_t)i * 96 + t];
        __syncthreads();
        const float si = s[i];
        const float4* dv4 = (const float4*)dvec;
        float e[3][4];
        float mloc = -3.4e38f;
        #pragma unroll
        for (int l = 0; l < 3; ++l) {
            int jv = t + l * 256;
            float4 d = dv4[jv];
            int j0 = jv * 4;
            unsigned int w = mrow[j0 >> 5];
            #pragma unroll
            for (int c = 0; c < 4; ++c) {
                int j = j0 + c;
                bool keep = (((w >> (j & 31)) & 1u) == 0u) && (j != i);
                float x = si + ((const float*)&d)[c];
                x = x > 0.f ? x : LRELU_ALPHA * x;
                e[l][c] = keep ? x : NEG_INF_F;
                mloc = fmaxf(mloc, e[l][c]);
            }
        }
        red[t] = mloc; __syncthreads();
        for (int o = 128; o; o >>= 1) {
            if (t < o) red[t] = fmaxf(red[t], red[t + o]);
            __syncthreads();
        }
        float m = red[0]; __syncthreads();
        float zloc = 0.f;
        #pragma unroll
        for (int l = 0; l < 3; ++l)
            #pragma unroll
            for (int c = 0; c < 4; ++c) { e[l][c] = expf(e[l][c] - m); zloc += e[l][c]; }
        red[t] = zloc; __syncthreads();
        for (int o = 128; o; o >>= 1) {
            if (t < o) red[t] += red[t + o];
            __syncthreads();
        }
        const float zinv = 1.f / red[0];
        #pragma unroll
        for (int l = 0; l < 3; ++l) {
            int jv = t + l * 256;
            ushort4v p;
            p.x = f2bf(e[l][0] * zinv); p.y = f2bf(e[l][1] * zinv);
            p.z = f2bf(e[l][2] * zinv); p.w = f2bf(e[l][3] * zinv);
            *(ushort4v*)(att + (size_t)i * N_V + (size_t)jv * 4) = p;
        }
    } else {
        const int i = blockIdx.x - N_V;
        const float* s = sd;
        const float* dvec = sd + N_V;
        const int cnt = deg[i];
        __shared__ float p[EDGE_CAP];
        __shared__ int lst[EDGE_CAP];
        float ev = -3.4e38f;
        if (t < cnt) {
            int j = edges[(size_t)i * EDGE_CAP + t];
            lst[t] = j;
            float x = s[i] + dvec[j];
            x = x > 0.f ? x : LRELU_ALPHA * x;
            p[t] = x;
            ev = x;
        }
        red[t] = ev; __syncthreads();
        for (int o = 128; o; o >>= 1) {
            if (t < o) red[t] = fmaxf(red[t], red[t + o]);
            __syncthreads();
        }
        float m = red[0]; __syncthreads();
        float pe = 0.f;
        if (t < cnt) { pe = expf(p[t] - m); p[t] = pe; }
        red[t] = pe; __syncthreads();
        for (int o = 128; o; o >>= 1) {
            if (t < o) red[t] += red[t + o];
            __syncthreads();
        }
        const float zinv = 1.f / red[0];
        float a0 = 0.f, a1 = 0.f;
        for (int e = 0; e < cnt; ++e) {
            int j = lst[e];
            float w = p[e] * zinv;
            ushort2v h = *(const ushort2v*)(Whn + (size_t)j * D_E + t * 2);
            a0 = fmaf(w, bf2f(h.x), a0);
            a1 = fmaf(w, bf2f(h.y), a1);
        }
        a0 = a0 > 0.f ? a0 : (expf(a0) - 1.f);
        a1 = a1 > 0.f ? a1 : (expf(a1) - 1.f);
        ushort2v o2; o2.x = f2bf(a0); o2.y = f2bf(a1);
        *(ushort2v*)(cat + (size_t)i * (2 * D_E) + t * 2) = o2;
    }
}

// ---------------------------------------------------------------------------
// Column sums of fp32 emb (for mean-centering).  grid 48, rows b*64..+63.
// ---------------------------------------------------------------------------
__global__ __launch_bounds__(256) void colsum(
    const float* __restrict__ emb, float* __restrict__ musum)
{
    const int b = blockIdx.x, t = threadIdx.x;
    float s0 = 0.f, s1 = 0.f;
    for (int r = 0; r < 64; ++r) {
        const float* row = emb + (size_t)(b * 64 + r) * D_E;
        s0 += row[t];
        s1 += row[t + 256];
    }
    atomicAdd(&musum[t], s0);
    atomicAdd(&musum[t + 256], s1);
}

// embc[i][c] = bf16(emb[i][c] - musum[c]/N)   (distance-preserving shift)
__global__ __launch_bounds__(256) void center_bf16(
    const float* __restrict__ emb, const float* __restrict__ musum,
    unsigned short* __restrict__ embc)
{
    int i = blockIdx.x * 256 + threadIdx.x;
    int c = i & (D_E - 1);
    embc[i] = f2bf(emb[i] - musum[c] * (1.f / N_V));
}

// ---------------------------------------------------------------------------
// Edge loss on centered bf16 via diff-form: d2 = sum (e_i - e_j)^2.
// No catastrophic cancellation; centered values are spread-sized so bf16
// rounding bias is negligible.  16-lane groups, row i staged in LDS.
// ---------------------------------------------------------------------------
__global__ __launch_bounds__(256) void edge_loss_c(
    const int* __restrict__ edges, const int* __restrict__ deg,
    const unsigned short* __restrict__ embc, float* __restrict__ accum)
{
    __shared__ unsigned short rowi[D_E];
    __shared__ float gsum[16];
    const int i = blockIdx.x, t = threadIdx.x;
    if (t < 64) ((bf16x8*)rowi)[t] = ((const bf16x8*)(embc + (size_t)i * D_E))[t];
    __syncthreads();
    const int g = t >> 4, l = t & 15;
    const int cnt = deg[i];
    float sum = 0.f;
    for (int e = g; e < cnt; e += 16) {
        int j = edges[(size_t)i * EDGE_CAP + e];
        float d2 = 0.f;
        #pragma unroll
        for (int q = 0; q < 4; ++q) {
            int off = q * 128 + l * 8;
            bf16x8 a = *(const bf16x8*)(rowi + off);
            bf16x8 b = *(const bf16x8*)(embc + (size_t)j * D_E + off);
            #pragma unroll
            for (int k = 0; k < 8; ++k) {
                float df = bf2f(((unsigned short*)&a)[k]) -
                           bf2f(((unsigned short*)&b)[k]);
                d2 = fmaf(df, df, d2);
            }
        }
        #pragma unroll
        for (int msk = 1; msk < 16; msk <<= 1) d2 += __shfl_xor(d2, msk);
        if (l == 0) sum += sqrtf(fmaxf(d2, 1e-12f));
    }
    if (l == 0) gsum[g] = sum;
    __syncthreads();
    if (t == 0) {
        float tot = 0.f;
        #pragma unroll
        for (int k = 0; k < 16; ++k) tot += gsum[k];
        atomicAdd(accum, -tot);
    }
}

// ---------------------------------------------------------------------------
// Glimpse confidence via bitmask (keep = bit): conf_i = 1/Z_i.
// ---------------------------------------------------------------------------
__global__ __launch_bounds__(256) void conf_kernel(
    const unsigned int* __restrict__ bitmask, const float* __restrict__ s,
    const float* __restrict__ dvec, float* __restrict__ accum)
{
    const int i = blockIdx.x, t = threadIdx.x;
    __shared__ unsigned int mrow[96];
    __shared__ float red[256];
    if (t < 96) mrow[t] = bitmask[(size_t)i * 96 + t];
    __syncthreads();
    const float si = s[i];
    const float4* dv4 = (const float4*)dvec;
    float e[3][4];
    float mloc = -3.4e38f;
    #pragma unroll
    for (int l = 0; l < 3; ++l) {
        int jv = t + l * 256;
        float4 d = dv4[jv];
        int j0 = jv * 4;
        unsigned int w = mrow[j0 >> 5];
        #pragma unroll
        for (int c = 0; c < 4; ++c) {
            int j = j0 + c;
            bool keep = ((w >> (j & 31)) & 1u) != 0u;
            float x = si + ((const float*)&d)[c];
            x = x > 0.f ? x : LRELU_ALPHA * x;
            e[l][c] = keep ? x : NEG_INF_F;
            mloc = fmaxf(mloc, e[l][c]);
        }
    }
    red[t] = mloc; __syncthreads();
    for (int o = 128; o; o >>= 1) {
        if (t < o) red[t] = fmaxf(red[t], red[t + o]);
        __syncthreads();
    }
    float m = red[0]; __syncthreads();
    float zloc = 0.f;
    #pragma unroll
    for (int l = 0; l < 3; ++l)
        #pragma unroll
        for (int c = 0; c < 4; ++c) zloc += expf(e[l][c] - m);
    red[t] = zloc; __syncthreads();
    for (int o = 128; o; o >>= 1) {
        if (t < o) red[t] += red[t + o];
        __syncthreads();
    }
    if (t == 0) atomicAdd(accum, logf(1.f / red[0] + 1e-8f));
}

__global__ void finalize(const float* __restrict__ accum, float* __restrict__ out)
{
    float loss = accum[0];
    out[0] = fmaxf(loss + 400.f, 0.f);
    out[1] = loss;
    out[2] = accum[1] / (float)N_V - logf(1e-8f);
}

// ---------------------------------------------------------------------------
extern "C" void kernel_launch(void* const* d_in, const int* in_sizes, int n_in,
                              void* d_out, int out_size, void* d_ws, size_t ws_size,
                              hipStream_t stream) {
    const float* emb_in   = (const float*)d_in[0];
    const float* adj      = (const float*)d_in[1];
    const float* W_n      = (const float*)d_in[2];
    const float* a_src_n  = (const float*)d_in[3];
    const float* a_dst_n  = (const float*)d_in[4];
    const float* W_nn     = (const float*)d_in[5];
    const float* a_src_nn = (const float*)d_in[6];
    const float* a_dst_nn = (const float*)d_in[7];
    const float* W_u      = (const float*)d_in[8];
    const float* b_u      = (const float*)d_in[9];
    const float* W_g      = (const float*)d_in[10];
    const float* a_src_g  = (const float*)d_in[11];
    const float* a_dst_g  = (const float*)d_in[12];
    float* out = (float*)d_out;

    char* p = (char*)d_ws;
    auto alloc = [&](size_t bytes) { char* r = p; p += (bytes + 255) & ~(size_t)255; return r; };

    unsigned short* att_nn  = (unsigned short*)alloc((size_t)N_V * N_V * 2);
    float*          Cp      = (float*)alloc((size_t)4 * N_V * D_E * 4);
    unsigned short* Whn     = (unsigned short*)alloc((size_t)N_V * D_E * 2);
    unsigned short* WhTnn   = (unsigned short*)alloc((size_t)D_E * N_V * 2);
    unsigned short* cat_bf  = (unsigned short*)alloc((size_t)N_V * 2 * D_E * 2);
    float*          embf[2] = { (float*)alloc((size_t)N_V * D_E * 4),
                                (float*)alloc((size_t)N_V * D_E * 4) };
    unsigned short* embb[2] = { (unsigned short*)alloc((size_t)N_V * D_E * 2),
                                (unsigned short*)alloc((size_t)N_V * D_E * 2) };
    unsigned short* embc    = (unsigned short*)alloc((size_t)N_V * D_E * 2);
    unsigned short* W2T     = (unsigned short*)alloc((size_t)(2 * D_E) * D_E * 2);
    unsigned short* WuT     = (unsigned short*)alloc((size_t)D_E * (2 * D_E) * 2);
    float*          wv      = (float*)alloc(6 * D_E * 4);
    float*          sd      = (float*)alloc(4 * N_V * 4);
    float*          sdg     = (float*)alloc(2 * N_V * 4);
    float*          musum   = (float*)alloc(D_E * 4);
    int*            edges   = (int*)alloc((size_t)N_V * EDGE_CAP * 4);
    int*            deg     = (int*)alloc(N_V * 4);
    unsigned int*   bitmask = (unsigned int*)alloc((size_t)N_V * 96 * 4);
    float*          accum   = (float*)alloc(2 * 4);

    dim3 blk(256);

    // one-time prepass
    convT_f32_bf16<<<dim3(2, D_E), blk, 0, stream>>>(W_n, W2T, D_E, D_E);
    convT_f32_bf16<<<dim3(2, D_E), blk, 0, stream>>>(W_nn, W2T + (size_t)D_E * D_E, D_E, D_E);
    convT_f32_bf16<<<dim3(4, D_E), blk, 0, stream>>>(W_u, WuT, 2 * D_E, D_E);
    conv_bf16<<<(N_V * D_E) / 256, blk, 0, stream>>>(emb_in, embb[0], N_V * D_E);
    hipMemcpyAsync(embf[0], emb_in, (size_t)N_V * D_E * 4, hipMemcpyDeviceToDevice, stream);
    hipMemsetAsync(accum, 0, 2 * sizeof(float), stream);
    hipMemsetAsync(musum, 0, D_E * sizeof(float), stream);
    build_graph<<<N_V, blk, 0, stream>>>(adj, edges, deg, bitmask);
    matvec6<<<D_E / 4, blk, 0, stream>>>(W_n, W_nn, W_g, a_src_n, a_dst_n,
                                         a_src_nn, a_dst_nn, a_src_g, a_dst_g, wv);

    dim3 gW2(16, N_V / 128);            // fused Wh GEMM (N=1024), 128x64 tile
    dim3 gG(8, N_V / 128);              // update GEMM (N=512), 128x64 tile
    dim3 gSK(4, N_V / 128, 4);          // nn GEMM, 128x128 tile, split-K=4

    int cur = 0;
    for (int it = 0; it < 10; ++it) {
        int nxt = cur ^ 1;
        sd_dots<4><<<N_V / 4, blk, 0, stream>>>(embb[cur], wv, sd);
        gemm_bf16<4><<<gW2, blk, 0, stream>>>(embb[cur], W2T, N_V, 2 * D_E, D_E,
                                              Whn, D_E, WhTnn, nullptr, nullptr, nullptr);
        nn_sm_gather<<<2 * N_V, blk, 0, stream>>>(bitmask, edges, deg, sd,
                                                  Whn, att_nn, cat_bf);
        gemm_bf16_sk<4><<<gSK, blk, 0, stream>>>(att_nn, WhTnn, N_V, D_E, N_V, Cp);
        elu_combine4<<<(N_V * D_E) / (4 * 256), blk, 0, stream>>>(Cp, cat_bf);
        gemm_bf16<2><<<gG, blk, 0, stream>>>(cat_bf, WuT, N_V, D_E, 2 * D_E,
                                             embb[nxt], D_E, nullptr, embf[cur], b_u, embf[nxt]);
        cur = nxt;
    }

    // losses: mean-center -> bf16 diff-form edge loss
    colsum<<<N_V / 64, blk, 0, stream>>>(embf[cur], musum);
    center_bf16<<<(N_V * D_E) / 256, blk, 0, stream>>>(embf[cur], musum, embc);
    edge_loss_c<<<N_V, blk, 0, stream>>>(edges, deg, embc, accum);
    sd_dots<2><<<N_V / 4, blk, 0, stream>>>(embb[cur], wv + 4 * D_E, sdg);
    conf_kernel<<<N_V, blk, 0, stream>>>(bitmask, sdg, sdg + N_V, accum + 1);

    finalize<<<1, 1, 0, stream>>>(accum, out);
}

// Round 8
// 884.569 us; speedup vs baseline: 1.9018x; 1.0312x over previous
//
#include <hip/hip_runtime.h>
#include <math.h>

#define N_V 3072
#define D_E 512
#define EDGE_CAP 128
constexpr float LRELU_ALPHA = 0.2f;
constexpr float NEG_INF_F = -9e15f;

typedef __attribute__((ext_vector_type(8))) short bf16x8;
typedef __attribute__((ext_vector_type(4))) float f32x4;
typedef __attribute__((ext_vector_type(4))) unsigned short ushort4v;
typedef __attribute__((ext_vector_type(2))) unsigned short ushort2v;

__device__ inline unsigned short f2bf(float f) {
    union { float f; unsigned int u; } x; x.f = f;
    unsigned int r = x.u + 0x7fffu + ((x.u >> 16) & 1u);
    return (unsigned short)(r >> 16);
}
__device__ inline float bf2f(unsigned short b) {
    union { unsigned int u; float f; } x; x.u = ((unsigned int)b) << 16;
    return x.f;
}

// XCD-aware bijective swizzle of the (bx,by) plane; nwg %8==0 for all grids
// here (384/192/384).
__device__ inline void xcd_swizzle(int& bx, int& by) {
    int gx = gridDim.x, nwg = gx * gridDim.y;
    int flat = by * gx + bx;
    int q = nwg >> 3;
    int swz = (flat & 7) * q + (flat >> 3);
    bx = swz % gx; by = swz / gx;
}

// ---------------------------------------------------------------------------
// bf16 MFMA GEMM: C[M,N] = A[M,K] @ B[K,N], B given TRANSPOSED (BT[N][K]).
// Tile 128x64, BK=64, 4 waves (2x2), wave tile 64x32, 16x16x32 MFMA.
// EPI 2: relu(acc + addv + bias) -> Cf (f32, ld=N) and C0 (bf16, ldc0).
// EPI 4: split: col<512 -> row-major bf16 C0 (ldc0=512);
//               col>=512 -> transposed bf16 C1 [(col-512)][M].
// ---------------------------------------------------------------------------
template<int EPI>
__global__ __launch_bounds__(256) void gemm_bf16(
    const unsigned short* __restrict__ A,   // [M][K] bf16
    const unsigned short* __restrict__ BT,  // [N][K] bf16
    int M, int N, int K,
    unsigned short* __restrict__ C0, int ldc0,
    unsigned short* __restrict__ C1,
    const float* __restrict__ addv,
    const float* __restrict__ bias,
    float* __restrict__ Cf)
{
    constexpr int BM = 128, BN = 64, BK = 64;
    __shared__ unsigned short As[BM * BK];
    __shared__ unsigned short Bs[BN * BK];
    const int tid  = threadIdx.x;
    int bxi = blockIdx.x, byi = blockIdx.y;
    xcd_swizzle(bxi, byi);
    const int bm   = byi * BM, bn = bxi * BN;
    const int lane = tid & 63, wid = tid >> 6;
    const int wr   = wid >> 1, wc = wid & 1;
    const int lr   = lane & 15, lk = lane >> 4;

    f32x4 acc[4][2];
    #pragma unroll
    for (int i = 0; i < 4; ++i)
        #pragma unroll
        for (int j = 0; j < 2; ++j)
            acc[i][j] = (f32x4)(0.f);

    auto asp = (__attribute__((address_space(3))) unsigned short*)As;
    auto bsp = (__attribute__((address_space(3))) unsigned short*)Bs;

    for (int k0 = 0; k0 < K; k0 += BK) {
        #pragma unroll
        for (int l = 0; l < 4; ++l) {
            int li = l * 256 + tid;
            int row = li >> 3, slot = li & 7;
            int gs = slot ^ (row & 7);
            __builtin_amdgcn_global_load_lds(
                (const __attribute__((address_space(1))) void*)(A + (size_t)(bm + row) * K + k0 + gs * 8),
                (__attribute__((address_space(3))) void*)(asp + li * 8), 16, 0, 0);
        }
        #pragma unroll
        for (int l = 0; l < 2; ++l) {
            int li = l * 256 + tid;
            int row = li >> 3, slot = li & 7;
            int gs = slot ^ (row & 7);
            __builtin_amdgcn_global_load_lds(
                (const __attribute__((address_space(1))) void*)(BT + (size_t)(bn + row) * K + k0 + gs * 8),
                (__attribute__((address_space(3))) void*)(bsp + li * 8), 16, 0, 0);
        }
        __syncthreads();

        #pragma unroll
        for (int ks = 0; ks < 2; ++ks) {
            bf16x8 af[4], bfr[2];
            #pragma unroll
            for (int fm = 0; fm < 4; ++fm) {
                int row = wr * 64 + fm * 16 + lr;
                int sl = (ks * 4 + lk) ^ (row & 7);
                af[fm] = *(const bf16x8*)(As + row * BK + sl * 8);
            }
            #pragma unroll
            for (int fn = 0; fn < 2; ++fn) {
                int col = wc * 32 + fn * 16 + lr;
                int sl = (ks * 4 + lk) ^ (col & 7);
                bfr[fn] = *(const bf16x8*)(Bs + col * BK + sl * 8);
            }
            #pragma unroll
            for (int fm = 0; fm < 4; ++fm)
                #pragma unroll
                for (int fn = 0; fn < 2; ++fn)
                    acc[fm][fn] = __builtin_amdgcn_mfma_f32_16x16x32_bf16(
                        af[fm], bfr[fn], acc[fm][fn], 0, 0, 0);
        }
        __syncthreads();
    }

    #pragma unroll
    for (int fm = 0; fm < 4; ++fm) {
        #pragma unroll
        for (int fn = 0; fn < 2; ++fn) {
            int row0 = bm + wr * 64 + fm * 16 + lk * 4;
            int col  = bn + wc * 32 + fn * 16 + lr;
            f32x4 v = acc[fm][fn];
            if (EPI == 2) {
                #pragma unroll
                for (int r = 0; r < 4; ++r) {
                    float x = v[r] + addv[(size_t)(row0 + r) * N + col] + bias[col];
                    x = x > 0.f ? x : 0.f;
                    Cf[(size_t)(row0 + r) * N + col] = x;
                    C0[(size_t)(row0 + r) * ldc0 + col] = f2bf(x);
                }
            } else { // EPI 4
                if (col < 512) {
                    #pragma unroll
                    for (int r = 0; r < 4; ++r)
                        C0[(size_t)(row0 + r) * ldc0 + col] = f2bf(v[r]);
                } else {
                    ushort4v p;
                    p.x = f2bf(v[0]); p.y = f2bf(v[1]);
                    p.z = f2bf(v[2]); p.w = f2bf(v[3]);
                    *(ushort4v*)(C1 + (size_t)(col - 512) * M + row0) = p;
                }
            }
        }
    }
}

// ---------------------------------------------------------------------------
// nn GEMM, single pass: C = att @ WhTnn^T, 64x64 tile, K=3072, fused ELU,
// writes bf16 into cat[:, 512:1024).  Grid (8, 48) = 384 blocks.
// ---------------------------------------------------------------------------
__global__ __launch_bounds__(256) void gemm_nn64(
    const unsigned short* __restrict__ A,    // att [3072][3072] bf16
    const unsigned short* __restrict__ BT,   // WhTnn [512][3072] bf16
    unsigned short* __restrict__ cat)
{
    constexpr int BM = 64, BN = 64, BK = 64, K = N_V;
    __shared__ unsigned short As[BM * BK];
    __shared__ unsigned short Bs[BN * BK];
    const int tid = threadIdx.x;
    int bxi = blockIdx.x, byi = blockIdx.y;
    xcd_swizzle(bxi, byi);
    const int bm = byi * BM, bn = bxi * BN;
    const int lane = tid & 63, wid = tid >> 6;
    const int wr = wid >> 1, wc = wid & 1;
    const int lr = lane & 15, lk = lane >> 4;

    f32x4 acc[2][2];
    #pragma unroll
    for (int i = 0; i < 2; ++i)
        #pragma unroll
        for (int j = 0; j < 2; ++j)
            acc[i][j] = (f32x4)(0.f);

    auto asp = (__attribute__((address_space(3))) unsigned short*)As;
    auto bsp = (__attribute__((address_space(3))) unsigned short*)Bs;

    for (int k0 = 0; k0 < K; k0 += BK) {
        #pragma unroll
        for (int l = 0; l < 2; ++l) {
            int li = l * 256 + tid;
            int row = li >> 3, slot = li & 7;
            int gs = slot ^ (row & 7);
            __builtin_amdgcn_global_load_lds(
                (const __attribute__((address_space(1))) void*)(A + (size_t)(bm + row) * K + k0 + gs * 8),
                (__attribute__((address_space(3))) void*)(asp + li * 8), 16, 0, 0);
        }
        #pragma unroll
        for (int l = 0; l < 2; ++l) {
            int li = l * 256 + tid;
            int row = li >> 3, slot = li & 7;
            int gs = slot ^ (row & 7);
            __builtin_amdgcn_global_load_lds(
                (const __attribute__((address_space(1))) void*)(BT + (size_t)(bn + row) * K + k0 + gs * 8),
                (__attribute__((address_space(3))) void*)(bsp + li * 8), 16, 0, 0);
        }
        __syncthreads();

        #pragma unroll
        for (int ks = 0; ks < 2; ++ks) {
            bf16x8 af[2], bfr[2];
            #pragma unroll
            for (int fm = 0; fm < 2; ++fm) {
                int row = wr * 32 + fm * 16 + lr;
                int sl = (ks * 4 + lk) ^ (row & 7);
                af[fm] = *(const bf16x8*)(As + row * BK + sl * 8);
            }
            #pragma unroll
            for (int fn = 0; fn < 2; ++fn) {
                int col = wc * 32 + fn * 16 + lr;
                int sl = (ks * 4 + lk) ^ (col & 7);
                bfr[fn] = *(const bf16x8*)(Bs + col * BK + sl * 8);
            }
            #pragma unroll
            for (int fm = 0; fm < 2; ++fm)
                #pragma unroll
                for (int fn = 0; fn < 2; ++fn)
                    acc[fm][fn] = __builtin_amdgcn_mfma_f32_16x16x32_bf16(
                        af[fm], bfr[fn], acc[fm][fn], 0, 0, 0);
        }
        __syncthreads();
    }

    #pragma unroll
    for (int fm = 0; fm < 2; ++fm) {
        #pragma unroll
        for (int fn = 0; fn < 2; ++fn) {
            int row0 = bm + wr * 32 + fm * 16 + lk * 4;
            int col  = bn + wc * 32 + fn * 16 + lr;
            #pragma unroll
            for (int r = 0; r < 4; ++r) {
                float x = acc[fm][fn][r];
                x = x > 0.f ? x : (expf(x) - 1.f);
                cat[(size_t)(row0 + r) * (2 * D_E) + D_E + col] = f2bf(x);
            }
        }
    }
}

// ---------------------------------------------------------------------------
// WT[n][k] = bf16(W[k][n]) ; flat bf16 convert
// ---------------------------------------------------------------------------
__global__ __launch_bounds__(256) void convT_f32_bf16(
    const float* __restrict__ W, unsigned short* __restrict__ WT, int K, int Nw)
{
    int k = blockIdx.x * 256 + threadIdx.x;
    int n = blockIdx.y;
    if (k < K) WT[(size_t)n * K + k] = f2bf(W[(size_t)k * Nw + n]);
}

__global__ __launch_bounds__(256) void conv_bf16(
    const float* __restrict__ X, unsigned short* __restrict__ Y, int n)
{
    int i = blockIdx.x * 256 + threadIdx.x;
    if (i < n) Y[i] = f2bf(X[i]);
}

// ---------------------------------------------------------------------------
// One-time: packed bitmask + deterministic per-row edge list.
// ---------------------------------------------------------------------------
__global__ __launch_bounds__(256) void build_graph(
    const float* __restrict__ adj, int* __restrict__ edges,
    int* __restrict__ deg, unsigned int* __restrict__ bitmask)
{
    const int i = blockIdx.x, t = threadIdx.x;
    __shared__ int cnts[256];
    unsigned int word = 0;
    int c = 0;
    if (t < 96) {
        #pragma unroll
        for (int b = 0; b < 32; ++b) {
            int j = t * 32 + b;
            if (adj[(size_t)i * N_V + j] > 0.f) { word |= (1u << b); ++c; }
        }
    }
    cnts[t] = c;
    __syncthreads();
    for (int o = 1; o < 256; o <<= 1) {
        int add = (t >= o) ? cnts[t - o] : 0;
        __syncthreads();
        cnts[t] += add;
        __syncthreads();
    }
    int base = cnts[t] - c;
    if (t < 96) {
        int k = 0;
        #pragma unroll
        for (int b = 0; b < 32; ++b) {
            if ((word >> b) & 1u) {
                int pos = base + k;
                if (pos < EDGE_CAP) edges[(size_t)i * EDGE_CAP + pos] = t * 32 + b;
                ++k;
            }
        }
        bitmask[(size_t)i * 96 + t] = word;
    }
    if (t == 0) deg[i] = cnts[255] < EDGE_CAP ? cnts[255] : EDGE_CAP;
}

// ---------------------------------------------------------------------------
// One-time: wv[0..5] = {W_n@as_n, W_n@ad_n, W_nn@as_nn, W_nn@ad_nn, W_g@as_g, W_g@ad_g}
// ---------------------------------------------------------------------------
__global__ __launch_bounds__(256) void matvec6(
    const float* __restrict__ W_n, const float* __restrict__ W_nn,
    const float* __restrict__ W_g,
    const float* __restrict__ as_n, const float* __restrict__ ad_n,
    const float* __restrict__ as_nn, const float* __restrict__ ad_nn,
    const float* __restrict__ as_g, const float* __restrict__ ad_g,
    float* __restrict__ wv)
{
    const int wave = threadIdx.x >> 6, lane = threadIdx.x & 63;
    const int r = blockIdx.x * 4 + wave;
    float a0 = 0, a1 = 0, a2 = 0, a3 = 0, a4 = 0, a5 = 0;
    #pragma unroll
    for (int k = 0; k < 8; ++k) {
        int c = lane + k * 64;
        float wn = W_n[(size_t)r * D_E + c];
        float wm = W_nn[(size_t)r * D_E + c];
        float wg = W_g[(size_t)r * D_E + c];
        a0 = fmaf(wn, as_n[c], a0);  a1 = fmaf(wn, ad_n[c], a1);
        a2 = fmaf(wm, as_nn[c], a2); a3 = fmaf(wm, ad_nn[c], a3);
        a4 = fmaf(wg, as_g[c], a4);  a5 = fmaf(wg, ad_g[c], a5);
    }
    #pragma unroll
    for (int off = 32; off; off >>= 1) {
        a0 += __shfl_down(a0, off); a1 += __shfl_down(a1, off);
        a2 += __shfl_down(a2, off); a3 += __shfl_down(a3, off);
        a4 += __shfl_down(a4, off); a5 += __shfl_down(a5, off);
    }
    if (lane == 0) {
        wv[0 * D_E + r] = a0; wv[1 * D_E + r] = a1;
        wv[2 * D_E + r] = a2; wv[3 * D_E + r] = a3;
        wv[4 * D_E + r] = a4; wv[5 * D_E + r] = a5;
    }
}

// ---------------------------------------------------------------------------
// outs[v][i] = emb_bf16[i,:] . wv[v]
// ---------------------------------------------------------------------------
template<int NV>
__global__ __launch_bounds__(256) void sd_dots(
    const unsigned short* __restrict__ emb, const float* __restrict__ wv,
    float* __restrict__ outs)
{
    const int wave = threadIdx.x >> 6, lane = threadIdx.x & 63;
    const int i = blockIdx.x * 4 + wave;
    float acc[NV];
    #pragma unroll
    for (int v = 0; v < NV; ++v) acc[v] = 0.f;
    #pragma unroll
    for (int k = 0; k < 8; ++k) {
        int c = lane + k * 64;
        float x = bf2f(emb[(size_t)i * D_E + c]);
        #pragma unroll
        for (int v = 0; v < NV; ++v) acc[v] = fmaf(x, wv[v * D_E + c], acc[v]);
    }
    #pragma unroll
    for (int off = 32; off; off >>= 1)
        #pragma unroll
        for (int v = 0; v < NV; ++v) acc[v] += __shfl_down(acc[v], off);
    if (lane == 0)
        #pragma unroll
        for (int v = 0; v < NV; ++v) outs[v * N_V + i] = acc[v];
}

// ---------------------------------------------------------------------------
// Fused: blocks [0,N_V) run non-neighbor softmax (writes att bf16);
// blocks [N_V,2N_V) run the sparse neighbor gather (writes cat[:,0:512]).
// sd layout: s_n = sd, d_n = sd+N, s_nn = sd+2N, d_nn = sd+3N.
// ---------------------------------------------------------------------------
__global__ __launch_bounds__(256) void nn_sm_gather(
    const unsigned int* __restrict__ bitmask,
    const int* __restrict__ edges, const int* __restrict__ deg,
    const float* __restrict__ sd,
    const unsigned short* __restrict__ Whn,
    unsigned short* __restrict__ att, unsigned short* __restrict__ cat)
{
    const int t = threadIdx.x;
    __shared__ float red[256];
    if (blockIdx.x < N_V) {
        const int i = blockIdx.x;
        const float* s = sd + 2 * N_V;
        const float* dvec = sd + 3 * N_V;
        __shared__ unsigned int mrow[96];
        if (t < 96) mrow[t] = bitmask[(size_t)i * 96 + t];
        __syncthreads();
        const float si = s[i];
        const float4* dv4 = (const float4*)dvec;
        float e[3][4];
        float mloc = -3.4e38f;
        #pragma unroll
        for (int l = 0; l < 3; ++l) {
            int jv = t + l * 256;
            float4 d = dv4[jv];
            int j0 = jv * 4;
            unsigned int w = mrow[j0 >> 5];
            #pragma unroll
            for (int c = 0; c < 4; ++c) {
                int j = j0 + c;
                bool keep = (((w >> (j & 31)) & 1u) == 0u) && (j != i);
                float x = si + ((const float*)&d)[c];
                x = x > 0.f ? x : LRELU_ALPHA * x;
                e[l][c] = keep ? x : NEG_INF_F;
                mloc = fmaxf(mloc, e[l][c]);
            }
        }
        red[t] = mloc; __syncthreads();
        for (int o = 128; o; o >>= 1) {
            if (t < o) red[t] = fmaxf(red[t], red[t + o]);
            __syncthreads();
        }
        float m = red[0]; __syncthreads();
        float zloc = 0.f;
        #pragma unroll
        for (int l = 0; l < 3; ++l)
            #pragma unroll
            for (int c = 0; c < 4; ++c) { e[l][c] = expf(e[l][c] - m); zloc += e[l][c]; }
        red[t] = zloc; __syncthreads();
        for (int o = 128; o; o >>= 1) {
            if (t < o) red[t] += red[t + o];
            __syncthreads();
        }
        const float zinv = 1.f / red[0];
        #pragma unroll
        for (int l = 0; l < 3; ++l) {
            int jv = t + l * 256;
            ushort4v p;
            p.x = f2bf(e[l][0] * zinv); p.y = f2bf(e[l][1] * zinv);
            p.z = f2bf(e[l][2] * zinv); p.w = f2bf(e[l][3] * zinv);
            *(ushort4v*)(att + (size_t)i * N_V + (size_t)jv * 4) = p;
        }
    } else {
        const int i = blockIdx.x - N_V;
        const float* s = sd;
        const float* dvec = sd + N_V;
        const int cnt = deg[i];
        __shared__ float p[EDGE_CAP];
        __shared__ int lst[EDGE_CAP];
        float ev = -3.4e38f;
        if (t < cnt) {
            int j = edges[(size_t)i * EDGE_CAP + t];
            lst[t] = j;
            float x = s[i] + dvec[j];
            x = x > 0.f ? x : LRELU_ALPHA * x;
            p[t] = x;
            ev = x;
        }
        red[t] = ev; __syncthreads();
        for (int o = 128; o; o >>= 1) {
            if (t < o) red[t] = fmaxf(red[t], red[t + o]);
            __syncthreads();
        }
        float m = red[0]; __syncthreads();
        float pe = 0.f;
        if (t < cnt) { pe = expf(p[t] - m); p[t] = pe; }
        red[t] = pe; __syncthreads();
        for (int o = 128; o; o >>= 1) {
            if (t < o) red[t] += red[t + o];
            __syncthreads();
        }
        const float zinv = 1.f / red[0];
        float a0 = 0.f, a1 = 0.f;
        for (int e = 0; e < cnt; ++e) {
            int j = lst[e];
            float w = p[e] * zinv;
            ushort2v h = *(const ushort2v*)(Whn + (size_t)j * D_E + t * 2);
            a0 = fmaf(w, bf2f(h.x), a0);
            a1 = fmaf(w, bf2f(h.y), a1);
        }
        a0 = a0 > 0.f ? a0 : (expf(a0) - 1.f);
        a1 = a1 > 0.f ? a1 : (expf(a1) - 1.f);
        ushort2v o2; o2.x = f2bf(a0); o2.y = f2bf(a1);
        *(ushort2v*)(cat + (size_t)i * (2 * D_E) + t * 2) = o2;
    }
}

// ---------------------------------------------------------------------------
// Column sums of fp32 emb (for mean-centering).
// ---------------------------------------------------------------------------
__global__ __launch_bounds__(256) void colsum(
    const float* __restrict__ emb, float* __restrict__ musum)
{
    const int b = blockIdx.x, t = threadIdx.x;
    float s0 = 0.f, s1 = 0.f;
    for (int r = 0; r < 64; ++r) {
        const float* row = emb + (size_t)(b * 64 + r) * D_E;
        s0 += row[t];
        s1 += row[t + 256];
    }
    atomicAdd(&musum[t], s0);
    atomicAdd(&musum[t + 256], s1);
}

// embc[i][c] = bf16(emb[i][c] - musum[c]/N)
__global__ __launch_bounds__(256) void center_bf16(
    const float* __restrict__ emb, const float* __restrict__ musum,
    unsigned short* __restrict__ embc)
{
    int i = blockIdx.x * 256 + threadIdx.x;
    int c = i & (D_E - 1);
    embc[i] = f2bf(emb[i] - musum[c] * (1.f / N_V));
}

// ---------------------------------------------------------------------------
// Edge loss on centered bf16 via diff-form.  Per-block partial to epart[i]
// (NO same-address atomics — they serialize across 3072 blocks).
// ---------------------------------------------------------------------------
__global__ __launch_bounds__(256) void edge_loss_c(
    const int* __restrict__ edges, const int* __restrict__ deg,
    const unsigned short* __restrict__ embc, float* __restrict__ epart)
{
    __shared__ unsigned short rowi[D_E];
    __shared__ float gsum[16];
    const int i = blockIdx.x, t = threadIdx.x;
    if (t < 64) ((bf16x8*)rowi)[t] = ((const bf16x8*)(embc + (size_t)i * D_E))[t];
    __syncthreads();
    const int g = t >> 4, l = t & 15;
    const int cnt = deg[i];
    float sum = 0.f;
    for (int e = g; e < cnt; e += 16) {
        int j = edges[(size_t)i * EDGE_CAP + e];
        float d2 = 0.f;
        #pragma unroll
        for (int q = 0; q < 4; ++q) {
            int off = q * 128 + l * 8;
            bf16x8 a = *(const bf16x8*)(rowi + off);
            bf16x8 b = *(const bf16x8*)(embc + (size_t)j * D_E + off);
            #pragma unroll
            for (int k = 0; k < 8; ++k) {
                float df = bf2f(((unsigned short*)&a)[k]) -
                           bf2f(((unsigned short*)&b)[k]);
                d2 = fmaf(df, df, d2);
            }
        }
        #pragma unroll
        for (int msk = 1; msk < 16; msk <<= 1) d2 += __shfl_xor(d2, msk);
        if (l == 0) sum += sqrtf(fmaxf(d2, 1e-12f));
    }
    if (l == 0) gsum[g] = sum;
    __syncthreads();
    if (t == 0) {
        float tot = 0.f;
        #pragma unroll
        for (int k = 0; k < 16; ++k) tot += gsum[k];
        epart[i] = tot;
    }
}

// ---------------------------------------------------------------------------
// Glimpse confidence via bitmask: cpart[i] = log(1/Z_i + 1e-8).
// ---------------------------------------------------------------------------
__global__ __launch_bounds__(256) void conf_kernel(
    const unsigned int* __restrict__ bitmask, const float* __restrict__ s,
    const float* __restrict__ dvec, float* __restrict__ cpart)
{
    const int i = blockIdx.x, t = threadIdx.x;
    __shared__ unsigned int mrow[96];
    __shared__ float red[256];
    if (t < 96) mrow[t] = bitmask[(size_t)i * 96 + t];
    __syncthreads();
    const float si = s[i];
    const float4* dv4 = (const float4*)dvec;
    float e[3][4];
    float mloc = -3.4e38f;
    #pragma unroll
    for (int l = 0; l < 3; ++l) {
        int jv = t + l * 256;
        float4 d = dv4[jv];
        int j0 = jv * 4;
        unsigned int w = mrow[j0 >> 5];
        #pragma unroll
        for (int c = 0; c < 4; ++c) {
            int j = j0 + c;
            bool keep = ((w >> (j & 31)) & 1u) != 0u;
            float x = si + ((const float*)&d)[c];
            x = x > 0.f ? x : LRELU_ALPHA * x;
            e[l][c] = keep ? x : NEG_INF_F;
            mloc = fmaxf(mloc, e[l][c]);
        }
    }
    red[t] = mloc; __syncthreads();
    for (int o = 128; o; o >>= 1) {
        if (t < o) red[t] = fmaxf(red[t], red[t + o]);
        __syncthreads();
    }
    float m = red[0]; __syncthreads();
    float zloc = 0.f;
    #pragma unroll
    for (int l = 0; l < 3; ++l)
        #pragma unroll
        for (int c = 0; c < 4; ++c) zloc += expf(e[l][c] - m);
    red[t] = zloc; __syncthreads();
    for (int o = 128; o; o >>= 1) {
        if (t < o) red[t] += red[t + o];
        __syncthreads();
    }
    if (t == 0) cpart[i] = logf(1.f / red[0] + 1e-8f);
}

// Final deterministic reduction of both partial arrays + output write.
__global__ __launch_bounds__(256) void finalize2(
    const float* __restrict__ epart, const float* __restrict__ cpart,
    float* __restrict__ out)
{
    const int t = threadIdx.x;
    float e = 0.f, c = 0.f;
    #pragma unroll
    for (int k = 0; k < 12; ++k) {
        e += epart[t + k * 256];
        c += cpart[t + k * 256];
    }
    __shared__ float re[256], rc[256];
    re[t] = e; rc[t] = c;
    __syncthreads();
    for (int o = 128; o; o >>= 1) {
        if (t < o) { re[t] += re[t + o]; rc[t] += rc[t + o]; }
        __syncthreads();
    }
    if (t == 0) {
        float loss = -re[0];
        out[0] = fmaxf(loss + 400.f, 0.f);
        out[1] = loss;
        out[2] = rc[0] / (float)N_V - logf(1e-8f);
    }
}

// ---------------------------------------------------------------------------
extern "C" void kernel_launch(void* const* d_in, const int* in_sizes, int n_in,
                              void* d_out, int out_size, void* d_ws, size_t ws_size,
                              hipStream_t stream) {
    const float* emb_in   = (const float*)d_in[0];
    const float* adj      = (const float*)d_in[1];
    const float* W_n      = (const float*)d_in[2];
    const float* a_src_n  = (const float*)d_in[3];
    const float* a_dst_n  = (const float*)d_in[4];
    const float* W_nn     = (const float*)d_in[5];
    const float* a_src_nn = (const float*)d_in[6];
    const float* a_dst_nn = (const float*)d_in[7];
    const float* W_u      = (const float*)d_in[8];
    const float* b_u      = (const float*)d_in[9];
    const float* W_g      = (const float*)d_in[10];
    const float* a_src_g  = (const float*)d_in[11];
    const float* a_dst_g  = (const float*)d_in[12];
    float* out = (float*)d_out;

    char* p = (char*)d_ws;
    auto alloc = [&](size_t bytes) { char* r = p; p += (bytes + 255) & ~(size_t)255; return r; };

    unsigned short* att_nn  = (unsigned short*)alloc((size_t)N_V * N_V * 2);
    unsigned short* Whn     = (unsigned short*)alloc((size_t)N_V * D_E * 2);
    unsigned short* WhTnn   = (unsigned short*)alloc((size_t)D_E * N_V * 2);
    unsigned short* cat_bf  = (unsigned short*)alloc((size_t)N_V * 2 * D_E * 2);
    float*          embf[2] = { (float*)alloc((size_t)N_V * D_E * 4),
                                (float*)alloc((size_t)N_V * D_E * 4) };
    unsigned short* embb[2] = { (unsigned short*)alloc((size_t)N_V * D_E * 2),
                                (unsigned short*)alloc((size_t)N_V * D_E * 2) };
    unsigned short* embc    = (unsigned short*)alloc((size_t)N_V * D_E * 2);
    unsigned short* W2T     = (unsigned short*)alloc((size_t)(2 * D_E) * D_E * 2);
    unsigned short* WuT     = (unsigned short*)alloc((size_t)D_E * (2 * D_E) * 2);
    float*          wv      = (float*)alloc(6 * D_E * 4);
    float*          sd      = (float*)alloc(4 * N_V * 4);
    float*          sdg     = (float*)alloc(2 * N_V * 4);
    float*          musum   = (float*)alloc(D_E * 4);
    float*          epart   = (float*)alloc(N_V * 4);
    float*          cpart   = (float*)alloc(N_V * 4);
    int*            edges   = (int*)alloc((size_t)N_V * EDGE_CAP * 4);
    int*            deg     = (int*)alloc(N_V * 4);
    unsigned int*   bitmask = (unsigned int*)alloc((size_t)N_V * 96 * 4);

    dim3 blk(256);

    // one-time prepass
    convT_f32_bf16<<<dim3(2, D_E), blk, 0, stream>>>(W_n, W2T, D_E, D_E);
    convT_f32_bf16<<<dim3(2, D_E), blk, 0, stream>>>(W_nn, W2T + (size_t)D_E * D_E, D_E, D_E);
    convT_f32_bf16<<<dim3(4, D_E), blk, 0, stream>>>(W_u, WuT, 2 * D_E, D_E);
    conv_bf16<<<(N_V * D_E) / 256, blk, 0, stream>>>(emb_in, embb[0], N_V * D_E);
    hipMemcpyAsync(embf[0], emb_in, (size_t)N_V * D_E * 4, hipMemcpyDeviceToDevice, stream);
    hipMemsetAsync(musum, 0, D_E * sizeof(float), stream);
    build_graph<<<N_V, blk, 0, stream>>>(adj, edges, deg, bitmask);
    matvec6<<<D_E / 4, blk, 0, stream>>>(W_n, W_nn, W_g, a_src_n, a_dst_n,
                                         a_src_nn, a_dst_nn, a_src_g, a_dst_g, wv);

    dim3 gW2(16, N_V / 128);            // fused Wh GEMM (N=1024), 128x64 tile
    dim3 gG(8, N_V / 128);              // update GEMM (N=512), 128x64 tile
    dim3 gNN(D_E / 64, N_V / 64);       // nn GEMM, 64x64 tile, single pass

    int cur = 0;
    for (int it = 0; it < 10; ++it) {
        int nxt = cur ^ 1;
        sd_dots<4><<<N_V / 4, blk, 0, stream>>>(embb[cur], wv, sd);
        gemm_bf16<4><<<gW2, blk, 0, stream>>>(embb[cur], W2T, N_V, 2 * D_E, D_E,
                                              Whn, D_E, WhTnn, nullptr, nullptr, nullptr);
        nn_sm_gather<<<2 * N_V, blk, 0, stream>>>(bitmask, edges, deg, sd,
                                                  Whn, att_nn, cat_bf);
        gemm_nn64<<<gNN, blk, 0, stream>>>(att_nn, WhTnn, cat_bf);
        gemm_bf16<2><<<gG, blk, 0, stream>>>(cat_bf, WuT, N_V, D_E, 2 * D_E,
                                             embb[nxt], D_E, nullptr, embf[cur], b_u, embf[nxt]);
        cur = nxt;
    }

    // losses: mean-center -> bf16 diff-form edge loss (per-block partials)
    colsum<<<N_V / 64, blk, 0, stream>>>(embf[cur], musum);
    center_bf16<<<(N_V * D_E) / 256, blk, 0, stream>>>(embf[cur], musum, embc);
    edge_loss_c<<<N_V, blk, 0, stream>>>(edges, deg, embc, epart);
    sd_dots<2><<<N_V / 4, blk, 0, stream>>>(embb[cur], wv + 4 * D_E, sdg);
    conf_kernel<<<N_V, blk, 0, stream>>>(bitmask, sdg, sdg + N_V, cpart);

    finalize2<<<1, blk, 0, stream>>>(epart, cpart, out);
}

// Round 10
// 853.767 us; speedup vs baseline: 1.9704x; 1.0361x over previous
//
#include <hip/hip_runtime.h>
#include <math.h>

#define N_V 3072
#define D_E 512
#define EDGE_CAP 128
constexpr float LRELU_ALPHA = 0.2f;
constexpr float NEG_INF_F = -9e15f;

typedef __attribute__((ext_vector_type(8))) short bf16x8;
typedef __attribute__((ext_vector_type(4))) float f32x4;
typedef __attribute__((ext_vector_type(4))) unsigned short ushort4v;
typedef __attribute__((ext_vector_type(2))) unsigned short ushort2v;

__device__ inline unsigned short f2bf(float f) {
    union { float f; unsigned int u; } x; x.f = f;
    unsigned int r = x.u + 0x7fffu + ((x.u >> 16) & 1u);
    return (unsigned short)(r >> 16);
}
__device__ inline float bf2f(unsigned short b) {
    union { unsigned int u; float f; } x; x.u = ((unsigned int)b) << 16;
    return x.f;
}

// XCD-aware bijective swizzle of the (bx,by) plane; nwg %8==0 for all grids
// here (408/192/384).
__device__ inline void xcd_swizzle(int& bx, int& by) {
    int gx = gridDim.x, nwg = gx * gridDim.y;
    int flat = by * gx + bx;
    int q = nwg >> 3;
    int swz = (flat & 7) * q + (flat >> 3);
    bx = swz % gx; by = swz / gx;
}

// ---------------------------------------------------------------------------
// bf16 MFMA GEMM: C[M,N] = A[M,K] @ B[K,N], B given TRANSPOSED (BT[N][K]).
// Tile 128x64, BK=64, 4 waves (2x2), wave tile 64x32, 16x16x32 MFMA.
// EPI 2: relu(acc + addv + bias) -> Cf (f32, ld=N) and C0 (bf16, ldc0).
// EPI 5: three-way split by block column:
//   bn < 512          : row-major bf16 C0 (ldc0)            [Wh_n]
//   512 <= bn < 1024  : LDS-transposed bf16 C1[(col-512)][M] (coalesced)
//   bn >= 1024        : cols 1024..1029 -> fp32 Cf[(col-1024)*N_V + row]
//                       (the 6 fused s/d dot products)
// ---------------------------------------------------------------------------
template<int EPI>
__global__ __launch_bounds__(256) void gemm_bf16(
    const unsigned short* __restrict__ A,   // [M][K] bf16
    const unsigned short* __restrict__ BT,  // [N][K] bf16
    int M, int N, int K,
    unsigned short* __restrict__ C0, int ldc0,
    unsigned short* __restrict__ C1,
    const float* __restrict__ addv,
    const float* __restrict__ bias,
    float* __restrict__ Cf)
{
    constexpr int BM = 128, BN = 64, BK = 64;
    __shared__ unsigned short As[BM * BK + BN * BK];   // unified; Ts reuses it
    unsigned short* Bs = As + BM * BK;
    const int tid  = threadIdx.x;
    int bxi = blockIdx.x, byi = blockIdx.y;
    xcd_swizzle(bxi, byi);
    const int bm   = byi * BM, bn = bxi * BN;
    const int lane = tid & 63, wid = tid >> 6;
    const int wr   = wid >> 1, wc = wid & 1;
    const int lr   = lane & 15, lk = lane >> 4;

    f32x4 acc[4][2];
    #pragma unroll
    for (int i = 0; i < 4; ++i)
        #pragma unroll
        for (int j = 0; j < 2; ++j)
            acc[i][j] = (f32x4)(0.f);

    auto asp = (__attribute__((address_space(3))) unsigned short*)As;
    auto bsp = (__attribute__((address_space(3))) unsigned short*)Bs;

    for (int k0 = 0; k0 < K; k0 += BK) {
        #pragma unroll
        for (int l = 0; l < 4; ++l) {
            int li = l * 256 + tid;
            int row = li >> 3, slot = li & 7;
            int gs = slot ^ (row & 7);
            __builtin_amdgcn_global_load_lds(
                (const __attribute__((address_space(1))) void*)(A + (size_t)(bm + row) * K + k0 + gs * 8),
                (__attribute__((address_space(3))) void*)(asp + li * 8), 16, 0, 0);
        }
        #pragma unroll
        for (int l = 0; l < 2; ++l) {
            int li = l * 256 + tid;
            int row = li >> 3, slot = li & 7;
            int gs = slot ^ (row & 7);
            __builtin_amdgcn_global_load_lds(
                (const __attribute__((address_space(1))) void*)(BT + (size_t)(bn + row) * K + k0 + gs * 8),
                (__attribute__((address_space(3))) void*)(bsp + li * 8), 16, 0, 0);
        }
        __syncthreads();

        #pragma unroll
        for (int ks = 0; ks < 2; ++ks) {
            bf16x8 af[4], bfr[2];
            #pragma unroll
            for (int fm = 0; fm < 4; ++fm) {
                int row = wr * 64 + fm * 16 + lr;
                int sl = (ks * 4 + lk) ^ (row & 7);
                af[fm] = *(const bf16x8*)(As + row * BK + sl * 8);
            }
            #pragma unroll
            for (int fn = 0; fn < 2; ++fn) {
                int col = wc * 32 + fn * 16 + lr;
                int sl = (ks * 4 + lk) ^ (col & 7);
                bfr[fn] = *(const bf16x8*)(Bs + col * BK + sl * 8);
            }
            #pragma unroll
            for (int fm = 0; fm < 4; ++fm)
                #pragma unroll
                for (int fn = 0; fn < 2; ++fn)
                    acc[fm][fn] = __builtin_amdgcn_mfma_f32_16x16x32_bf16(
                        af[fm], bfr[fn], acc[fm][fn], 0, 0, 0);
        }
        __syncthreads();
    }

    if (EPI == 2) {
        #pragma unroll
        for (int fm = 0; fm < 4; ++fm) {
            #pragma unroll
            for (int fn = 0; fn < 2; ++fn) {
                int row0 = bm + wr * 64 + fm * 16 + lk * 4;
                int col  = bn + wc * 32 + fn * 16 + lr;
                f32x4 v = acc[fm][fn];
                #pragma unroll
                for (int r = 0; r < 4; ++r) {
                    float x = v[r] + addv[(size_t)(row0 + r) * N + col] + bias[col];
                    x = x > 0.f ? x : 0.f;
                    Cf[(size_t)(row0 + r) * N + col] = x;
                    C0[(size_t)(row0 + r) * ldc0 + col] = f2bf(x);
                }
            }
        }
    } else { // EPI 5
        if (bn < 512) {
            #pragma unroll
            for (int fm = 0; fm < 4; ++fm) {
                #pragma unroll
                for (int fn = 0; fn < 2; ++fn) {
                    int row0 = bm + wr * 64 + fm * 16 + lk * 4;
                    int col  = bn + wc * 32 + fn * 16 + lr;
                    #pragma unroll
                    for (int r = 0; r < 4; ++r)
                        C0[(size_t)(row0 + r) * ldc0 + col] = f2bf(acc[fm][fn][r]);
                }
            }
        } else if (bn < 1024) {
            // stage 128x64 tile transposed into LDS (Ts[64][136]), then
            // coalesced 16B stores along WhTnn rows.
            constexpr int TS = 136;
            unsigned short* Ts = As;
            #pragma unroll
            for (int fm = 0; fm < 4; ++fm) {
                #pragma unroll
                for (int fn = 0; fn < 2; ++fn) {
                    int rloc = wr * 64 + fm * 16 + lk * 4;     // local row 0..127
                    int lc   = wc * 32 + fn * 16 + lr;         // local col 0..63
                    ushort4v pk;
                    pk.x = f2bf(acc[fm][fn][0]); pk.y = f2bf(acc[fm][fn][1]);
                    pk.z = f2bf(acc[fm][fn][2]); pk.w = f2bf(acc[fm][fn][3]);
                    *(ushort4v*)(Ts + lc * TS + rloc) = pk;
                }
            }
            __syncthreads();
            for (int idx = tid; idx < 64 * 16; idx += 256) {
                int c = idx >> 4, seg = idx & 15;
                // 16-byte (8-short) copy: seg strides by 8 shorts.
                bf16x8 pk = *(const bf16x8*)(Ts + c * TS + seg * 8);
                *(bf16x8*)(C1 + (size_t)(bn - 512 + c) * M + bm + seg * 8) = pk;
            }
        } else {
            // s/d fused dot-product columns (1024..1029)
            #pragma unroll
            for (int fm = 0; fm < 4; ++fm) {
                #pragma unroll
                for (int fn = 0; fn < 2; ++fn) {
                    int row0 = bm + wr * 64 + fm * 16 + lk * 4;
                    int col  = bn + wc * 32 + fn * 16 + lr;
                    if (col >= 1024 && col < 1030) {
                        int v = col - 1024;
                        #pragma unroll
                        for (int r = 0; r < 4; ++r)
                            Cf[(size_t)v * N_V + row0 + r] = acc[fm][fn][r];
                    }
                }
            }
        }
    }
}

// ---------------------------------------------------------------------------
// nn GEMM, single pass: C = att @ WhTnn^T, 64x64 tile, K=3072, fused ELU,
// writes bf16 into cat[:, 512:1024).  Grid (8, 48) = 384 blocks.
// ---------------------------------------------------------------------------
__global__ __launch_bounds__(256) void gemm_nn64(
    const unsigned short* __restrict__ A,    // att [3072][3072] bf16
    const unsigned short* __restrict__ BT,   // WhTnn [512][3072] bf16
    unsigned short* __restrict__ cat)
{
    constexpr int BM = 64, BN = 64, BK = 64, K = N_V;
    __shared__ unsigned short As[BM * BK];
    __shared__ unsigned short Bs[BN * BK];
    const int tid = threadIdx.x;
    int bxi = blockIdx.x, byi = blockIdx.y;
    xcd_swizzle(bxi, byi);
    const int bm = byi * BM, bn = bxi * BN;
    const int lane = tid & 63, wid = tid >> 6;
    const int wr = wid >> 1, wc = wid & 1;
    const int lr = lane & 15, lk = lane >> 4;

    f32x4 acc[2][2];
    #pragma unroll
    for (int i = 0; i < 2; ++i)
        #pragma unroll
        for (int j = 0; j < 2; ++j)
            acc[i][j] = (f32x4)(0.f);

    auto asp = (__attribute__((address_space(3))) unsigned short*)As;
    auto bsp = (__attribute__((address_space(3))) unsigned short*)Bs;

    for (int k0 = 0; k0 < K; k0 += BK) {
        #pragma unroll
        for (int l = 0; l < 2; ++l) {
            int li = l * 256 + tid;
            int row = li >> 3, slot = li & 7;
            int gs = slot ^ (row & 7);
            __builtin_amdgcn_global_load_lds(
                (const __attribute__((address_space(1))) void*)(A + (size_t)(bm + row) * K + k0 + gs * 8),
                (__attribute__((address_space(3))) void*)(asp + li * 8), 16, 0, 0);
        }
        #pragma unroll
        for (int l = 0; l < 2; ++l) {
            int li = l * 256 + tid;
            int row = li >> 3, slot = li & 7;
            int gs = slot ^ (row & 7);
            __builtin_amdgcn_global_load_lds(
                (const __attribute__((address_space(1))) void*)(BT + (size_t)(bn + row) * K + k0 + gs * 8),
                (__attribute__((address_space(3))) void*)(bsp + li * 8), 16, 0, 0);
        }
        __syncthreads();

        #pragma unroll
        for (int ks = 0; ks < 2; ++ks) {
            bf16x8 af[2], bfr[2];
            #pragma unroll
            for (int fm = 0; fm < 2; ++fm) {
                int row = wr * 32 + fm * 16 + lr;
                int sl = (ks * 4 + lk) ^ (row & 7);
                af[fm] = *(const bf16x8*)(As + row * BK + sl * 8);
            }
            #pragma unroll
            for (int fn = 0; fn < 2; ++fn) {
                int col = wc * 32 + fn * 16 + lr;
                int sl = (ks * 4 + lk) ^ (col & 7);
                bfr[fn] = *(const bf16x8*)(Bs + col * BK + sl * 8);
            }
            #pragma unroll
            for (int fm = 0; fm < 2; ++fm)
                #pragma unroll
                for (int fn = 0; fn < 2; ++fn)
                    acc[fm][fn] = __builtin_amdgcn_mfma_f32_16x16x32_bf16(
                        af[fm], bfr[fn], acc[fm][fn], 0, 0, 0);
        }
        __syncthreads();
    }

    #pragma unroll
    for (int fm = 0; fm < 2; ++fm) {
        #pragma unroll
        for (int fn = 0; fn < 2; ++fn) {
            int row0 = bm + wr * 32 + fm * 16 + lk * 4;
            int col  = bn + wc * 32 + fn * 16 + lr;
            #pragma unroll
            for (int r = 0; r < 4; ++r) {
                float x = acc[fm][fn][r];
                x = x > 0.f ? x : (expf(x) - 1.f);
                cat[(size_t)(row0 + r) * (2 * D_E) + D_E + col] = f2bf(x);
            }
        }
    }
}

// ---------------------------------------------------------------------------
// WT[n][k] = bf16(W[k][n]) ; wv rows -> bf16 into W2Tx[1024+v]
// ---------------------------------------------------------------------------
__global__ __launch_bounds__(256) void convT_f32_bf16(
    const float* __restrict__ W, unsigned short* __restrict__ WT, int K, int Nw)
{
    int k = blockIdx.x * 256 + threadIdx.x;
    int n = blockIdx.y;
    if (k < K) WT[(size_t)n * K + k] = f2bf(W[(size_t)k * Nw + n]);
}

__global__ __launch_bounds__(256) void conv_bf16(
    const float* __restrict__ X, unsigned short* __restrict__ Y, int n)
{
    int i = blockIdx.x * 256 + threadIdx.x;
    if (i < n) Y[i] = f2bf(X[i]);
}

__global__ __launch_bounds__(256) void conv_wv_rows(
    const float* __restrict__ wv, unsigned short* __restrict__ W2Tx)
{
    int k = threadIdx.x + (blockIdx.x & 1) * 256;
    int v = blockIdx.x >> 1;
    W2Tx[(size_t)(1024 + v) * D_E + k] = f2bf(wv[v * D_E + k]);
}

// ---------------------------------------------------------------------------
// One-time: packed bitmask + deterministic per-row edge list.
// ---------------------------------------------------------------------------
__global__ __launch_bounds__(256) void build_graph(
    const float* __restrict__ adj, int* __restrict__ edges,
    int* __restrict__ deg, unsigned int* __restrict__ bitmask)
{
    const int i = blockIdx.x, t = threadIdx.x;
    __shared__ int cnts[256];
    unsigned int word = 0;
    int c = 0;
    if (t < 96) {
        #pragma unroll
        for (int b = 0; b < 32; ++b) {
            int j = t * 32 + b;
            if (adj[(size_t)i * N_V + j] > 0.f) { word |= (1u << b); ++c; }
        }
    }
    cnts[t] = c;
    __syncthreads();
    for (int o = 1; o < 256; o <<= 1) {
        int add = (t >= o) ? cnts[t - o] : 0;
        __syncthreads();
        cnts[t] += add;
        __syncthreads();
    }
    int base = cnts[t] - c;
    if (t < 96) {
        int k = 0;
        #pragma unroll
        for (int b = 0; b < 32; ++b) {
            if ((word >> b) & 1u) {
                int pos = base + k;
                if (pos < EDGE_CAP) edges[(size_t)i * EDGE_CAP + pos] = t * 32 + b;
                ++k;
            }
        }
        bitmask[(size_t)i * 96 + t] = word;
    }
    if (t == 0) deg[i] = cnts[255] < EDGE_CAP ? cnts[255] : EDGE_CAP;
}

// ---------------------------------------------------------------------------
// One-time: wv[0..5] = {W_n@as_n, W_n@ad_n, W_nn@as_nn, W_nn@ad_nn, W_g@as_g, W_g@ad_g}
// ---------------------------------------------------------------------------
__global__ __launch_bounds__(256) void matvec6(
    const float* __restrict__ W_n, const float* __restrict__ W_nn,
    const float* __restrict__ W_g,
    const float* __restrict__ as_n, const float* __restrict__ ad_n,
    const float* __restrict__ as_nn, const float* __restrict__ ad_nn,
    const float* __restrict__ as_g, const float* __restrict__ ad_g,
    float* __restrict__ wv)
{
    const int wave = threadIdx.x >> 6, lane = threadIdx.x & 63;
    const int r = blockIdx.x * 4 + wave;
    float a0 = 0, a1 = 0, a2 = 0, a3 = 0, a4 = 0, a5 = 0;
    #pragma unroll
    for (int k = 0; k < 8; ++k) {
        int c = lane + k * 64;
        float wn = W_n[(size_t)r * D_E + c];
        float wm = W_nn[(size_t)r * D_E + c];
        float wg = W_g[(size_t)r * D_E + c];
        a0 = fmaf(wn, as_n[c], a0);  a1 = fmaf(wn, ad_n[c], a1);
        a2 = fmaf(wm, as_nn[c], a2); a3 = fmaf(wm, ad_nn[c], a3);
        a4 = fmaf(wg, as_g[c], a4);  a5 = fmaf(wg, ad_g[c], a5);
    }
    #pragma unroll
    for (int off = 32; off; off >>= 1) {
        a0 += __shfl_down(a0, off); a1 += __shfl_down(a1, off);
        a2 += __shfl_down(a2, off); a3 += __shfl_down(a3, off);
        a4 += __shfl_down(a4, off); a5 += __shfl_down(a5, off);
    }
    if (lane == 0) {
        wv[0 * D_E + r] = a0; wv[1 * D_E + r] = a1;
        wv[2 * D_E + r] = a2; wv[3 * D_E + r] = a3;
        wv[4 * D_E + r] = a4; wv[5 * D_E + r] = a5;
    }
}

// ---------------------------------------------------------------------------
// outs[v][i] = emb_bf16[i,:] . wv[v]   (used post-loop for glimpse only)
// ---------------------------------------------------------------------------
template<int NV>
__global__ __launch_bounds__(256) void sd_dots(
    const unsigned short* __restrict__ emb, const float* __restrict__ wv,
    float* __restrict__ outs)
{
    const int wave = threadIdx.x >> 6, lane = threadIdx.x & 63;
    const int i = blockIdx.x * 4 + wave;
    float acc[NV];
    #pragma unroll
    for (int v = 0; v < NV; ++v) acc[v] = 0.f;
    #pragma unroll
    for (int k = 0; k < 8; ++k) {
        int c = lane + k * 64;
        float x = bf2f(emb[(size_t)i * D_E + c]);
        #pragma unroll
        for (int v = 0; v < NV; ++v) acc[v] = fmaf(x, wv[v * D_E + c], acc[v]);
    }
    #pragma unroll
    for (int off = 32; off; off >>= 1)
        #pragma unroll
        for (int v = 0; v < NV; ++v) acc[v] += __shfl_down(acc[v], off);
    if (lane == 0)
        #pragma unroll
        for (int v = 0; v < NV; ++v) outs[v * N_V + i] = acc[v];
}

// ---------------------------------------------------------------------------
// Fused: blocks [0,N_V) run non-neighbor softmax (writes att bf16);
// blocks [N_V,2N_V) run the sparse neighbor gather (writes cat[:,0:512]).
// sd layout: s_n = sd, d_n = sd+N, s_nn = sd+2N, d_nn = sd+3N.
// ---------------------------------------------------------------------------
__global__ __launch_bounds__(256) void nn_sm_gather(
    const unsigned int* __restrict__ bitmask,
    const int* __restrict__ edges, const int* __restrict__ deg,
    const float* __restrict__ sd,
    const unsigned short* __restrict__ Whn,
    unsigned short* __restrict__ att, unsigned short* __restrict__ cat)
{
    const int t = threadIdx.x;
    __shared__ float red[256];
    if (blockIdx.x < N_V) {
        const int i = blockIdx.x;
        const float* s = sd + 2 * N_V;
        const float* dvec = sd + 3 * N_V;
        __shared__ unsigned int mrow[96];
        if (t < 96) mrow[t] = bitmask[(size_t)i * 96 + t];
        __syncthreads();
        const float si = s[i];
        const float4* dv4 = (const float4*)dvec;
        float e[3][4];
        float mloc = -3.4e38f;
        #pragma unroll
        for (int l = 0; l < 3; ++l) {
            int jv = t + l * 256;
            float4 d = dv4[jv];
            int j0 = jv * 4;
            unsigned int w = mrow[j0 >> 5];
            #pragma unroll
            for (int c = 0; c < 4; ++c) {
                int j = j0 + c;
                bool keep = (((w >> (j & 31)) & 1u) == 0u) && (j != i);
                float x = si + ((const float*)&d)[c];
                x = x > 0.f ? x : LRELU_ALPHA * x;
                e[l][c] = keep ? x : NEG_INF_F;
                mloc = fmaxf(mloc, e[l][c]);
            }
        }
        red[t] = mloc; __syncthreads();
        for (int o = 128; o; o >>= 1) {
            if (t < o) red[t] = fmaxf(red[t], red[t + o]);
            __syncthreads();
        }
        float m = red[0]; __syncthreads();
        float zloc = 0.f;
        #pragma unroll
        for (int l = 0; l < 3; ++l)
            #pragma unroll
            for (int c = 0; c < 4; ++c) { e[l][c] = expf(e[l][c] - m); zloc += e[l][c]; }
        red[t] = zloc; __syncthreads();
        for (int o = 128; o; o >>= 1) {
            if (t < o) red[t] += red[t + o];
            __syncthreads();
        }
        const float zinv = 1.f / red[0];
        #pragma unroll
        for (int l = 0; l < 3; ++l) {
            int jv = t + l * 256;
            ushort4v p;
            p.x = f2bf(e[l][0] * zinv); p.y = f2bf(e[l][1] * zinv);
            p.z = f2bf(e[l][2] * zinv); p.w = f2bf(e[l][3] * zinv);
            *(ushort4v*)(att + (size_t)i * N_V + (size_t)jv * 4) = p;
        }
    } else {
        const int i = blockIdx.x - N_V;
        const float* s = sd;
        const float* dvec = sd + N_V;
        const int cnt = deg[i];
        __shared__ float p[EDGE_CAP];
        __shared__ int lst[EDGE_CAP];
        float ev = -3.4e38f;
        if (t < cnt) {
            int j = edges[(size_t)i * EDGE_CAP + t];
            lst[t] = j;
            float x = s[i] + dvec[j];
            x = x > 0.f ? x : LRELU_ALPHA * x;
            p[t] = x;
            ev = x;
        }
        red[t] = ev; __syncthreads();
        for (int o = 128; o; o >>= 1) {
            if (t < o) red[t] = fmaxf(red[t], red[t + o]);
            __syncthreads();
        }
        float m = red[0]; __syncthreads();
        float pe = 0.f;
        if (t < cnt) { pe = expf(p[t] - m); p[t] = pe; }
        red[t] = pe; __syncthreads();
        for (int o = 128; o; o >>= 1) {
            if (t < o) red[t] += red[t + o];
            __syncthreads();
        }
        const float zinv = 1.f / red[0];
        float a0 = 0.f, a1 = 0.f;
        for (int e = 0; e < cnt; ++e) {
            int j = lst[e];
            float w = p[e] * zinv;
            ushort2v h = *(const ushort2v*)(Whn + (size_t)j * D_E + t * 2);
            a0 = fmaf(w, bf2f(h.x), a0);
            a1 = fmaf(w, bf2f(h.y), a1);
        }
        a0 = a0 > 0.f ? a0 : (expf(a0) - 1.f);
        a1 = a1 > 0.f ? a1 : (expf(a1) - 1.f);
        ushort2v o2; o2.x = f2bf(a0); o2.y = f2bf(a1);
        *(ushort2v*)(cat + (size_t)i * (2 * D_E) + t * 2) = o2;
    }
}

// ---------------------------------------------------------------------------
// Column sums of fp32 emb (for mean-centering).
// ---------------------------------------------------------------------------
__global__ __launch_bounds__(256) void colsum(
    const float* __restrict__ emb, float* __restrict__ musum)
{
    const int b = blockIdx.x, t = threadIdx.x;
    float s0 = 0.f, s1 = 0.f;
    for (int r = 0; r < 64; ++r) {
        const float* row = emb + (size_t)(b * 64 + r) * D_E;
        s0 += row[t];
        s1 += row[t + 256];
    }
    atomicAdd(&musum[t], s0);
    atomicAdd(&musum[t + 256], s1);
}

// embc[i][c] = bf16(emb[i][c] - musum[c]/N)
__global__ __launch_bounds__(256) void center_bf16(
    const float* __restrict__ emb, const float* __restrict__ musum,
    unsigned short* __restrict__ embc)
{
    int i = blockIdx.x * 256 + threadIdx.x;
    int c = i & (D_E - 1);
    embc[i] = f2bf(emb[i] - musum[c] * (1.f / N_V));
}

// ---------------------------------------------------------------------------
// Edge loss on centered bf16 via diff-form; per-block partial to epart[i].
// ---------------------------------------------------------------------------
__global__ __launch_bounds__(256) void edge_loss_c(
    const int* __restrict__ edges, const int* __restrict__ deg,
    const unsigned short* __restrict__ embc, float* __restrict__ epart)
{
    __shared__ unsigned short rowi[D_E];
    __shared__ float gsum[16];
    const int i = blockIdx.x, t = threadIdx.x;
    if (t < 64) ((bf16x8*)rowi)[t] = ((const bf16x8*)(embc + (size_t)i * D_E))[t];
    __syncthreads();
    const int g = t >> 4, l = t & 15;
    const int cnt = deg[i];
    float sum = 0.f;
    for (int e = g; e < cnt; e += 16) {
        int j = edges[(size_t)i * EDGE_CAP + e];
        float d2 = 0.f;
        #pragma unroll
        for (int q = 0; q < 4; ++q) {
            int off = q * 128 + l * 8;
            bf16x8 a = *(const bf16x8*)(rowi + off);
            bf16x8 b = *(const bf16x8*)(embc + (size_t)j * D_E + off);
            #pragma unroll
            for (int k = 0; k < 8; ++k) {
                float df = bf2f(((unsigned short*)&a)[k]) -
                           bf2f(((unsigned short*)&b)[k]);
                d2 = fmaf(df, df, d2);
            }
        }
        #pragma unroll
        for (int msk = 1; msk < 16; msk <<= 1) d2 += __shfl_xor(d2, msk);
        if (l == 0) sum += sqrtf(fmaxf(d2, 1e-12f));
    }
    if (l == 0) gsum[g] = sum;
    __syncthreads();
    if (t == 0) {
        float tot = 0.f;
        #pragma unroll
        for (int k = 0; k < 16; ++k) tot += gsum[k];
        epart[i] = tot;
    }
}

// ---------------------------------------------------------------------------
// Glimpse confidence via bitmask: cpart[i] = log(1/Z_i + 1e-8).
// ---------------------------------------------------------------------------
__global__ __launch_bounds__(256) void conf_kernel(
    const unsigned int* __restrict__ bitmask, const float* __restrict__ s,
    const float* __restrict__ dvec, float* __restrict__ cpart)
{
    const int i = blockIdx.x, t = threadIdx.x;
    __shared__ unsigned int mrow[96];
    __shared__ float red[256];
    if (t < 96) mrow[t] = bitmask[(size_t)i * 96 + t];
    __syncthreads();
    const float si = s[i];
    const float4* dv4 = (const float4*)dvec;
    float e[3][4];
    float mloc = -3.4e38f;
    #pragma unroll
    for (int l = 0; l < 3; ++l) {
        int jv = t + l * 256;
        float4 d = dv4[jv];
        int j0 = jv * 4;
        unsigned int w = mrow[j0 >> 5];
        #pragma unroll
        for (int c = 0; c < 4; ++c) {
            int j = j0 + c;
            bool keep = ((w >> (j & 31)) & 1u) != 0u;
            float x = si + ((const float*)&d)[c];
            x = x > 0.f ? x : LRELU_ALPHA * x;
            e[l][c] = keep ? x : NEG_INF_F;
            mloc = fmaxf(mloc, e[l][c]);
        }
    }
    red[t] = mloc; __syncthreads();
    for (int o = 128; o; o >>= 1) {
        if (t < o) red[t] = fmaxf(red[t], red[t + o]);
        __syncthreads();
    }
    float m = red[0]; __syncthreads();
    float zloc = 0.f;
    #pragma unroll
    for (int l = 0; l < 3; ++l)
        #pragma unroll
        for (int c = 0; c < 4; ++c) zloc += expf(e[l][c] - m);
    red[t] = zloc; __syncthreads();
    for (int o = 128; o; o >>= 1) {
        if (t < o) red[t] += red[t + o];
        __syncthreads();
    }
    if (t == 0) cpart[i] = logf(1.f / red[0] + 1e-8f);
}

// Final deterministic reduction of both partial arrays + output write.
__global__ __launch_bounds__(256) void finalize2(
    const float* __restrict__ epart, const float* __restrict__ cpart,
    float* __restrict__ out)
{
    const int t = threadIdx.x;
    float e = 0.f, c = 0.f;
    #pragma unroll
    for (int k = 0; k < 12; ++k) {
        e += epart[t + k * 256];
        c += cpart[t + k * 256];
    }
    __shared__ float re[256], rc[256];
    re[t] = e; rc[t] = c;
    __syncthreads();
    for (int o = 128; o; o >>= 1) {
        if (t < o) { re[t] += re[t + o]; rc[t] += rc[t + o]; }
        __syncthreads();
    }
    if (t == 0) {
        float loss = -re[0];
        out[0] = fmaxf(loss + 400.f, 0.f);
        out[1] = loss;
        out[2] = rc[0] / (float)N_V - logf(1e-8f);
    }
}

// ---------------------------------------------------------------------------
extern "C" void kernel_launch(void* const* d_in, const int* in_sizes, int n_in,
                              void* d_out, int out_size, void* d_ws, size_t ws_size,
                              hipStream_t stream) {
    const float* emb_in   = (const float*)d_in[0];
    const float* adj      = (const float*)d_in[1];
    const float* W_n      = (const float*)d_in[2];
    const float* a_src_n  = (const float*)d_in[3];
    const float* a_dst_n  = (const float*)d_in[4];
    const float* W_nn     = (const float*)d_in[5];
    const float* a_src_nn = (const float*)d_in[6];
    const float* a_dst_nn = (const float*)d_in[7];
    const float* W_u      = (const float*)d_in[8];
    const float* b_u      = (const float*)d_in[9];
    const float* W_g      = (const float*)d_in[10];
    const float* a_src_g  = (const float*)d_in[11];
    const float* a_dst_g  = (const float*)d_in[12];
    float* out = (float*)d_out;

    char* p = (char*)d_ws;
    auto alloc = [&](size_t bytes) { char* r = p; p += (bytes + 255) & ~(size_t)255; return r; };

    unsigned short* att_nn  = (unsigned short*)alloc((size_t)N_V * N_V * 2);
    unsigned short* Whn     = (unsigned short*)alloc((size_t)N_V * D_E * 2);
    unsigned short* WhTnn   = (unsigned short*)alloc((size_t)D_E * N_V * 2);
    unsigned short* cat_bf  = (unsigned short*)alloc((size_t)N_V * 2 * D_E * 2);
    float*          embf[2] = { (float*)alloc((size_t)N_V * D_E * 4),
                                (float*)alloc((size_t)N_V * D_E * 4) };
    unsigned short* embb[2] = { (unsigned short*)alloc((size_t)N_V * D_E * 2),
                                (unsigned short*)alloc((size_t)N_V * D_E * 2) };
    unsigned short* embc    = (unsigned short*)alloc((size_t)N_V * D_E * 2);
    unsigned short* W2Tx    = (unsigned short*)alloc((size_t)1088 * D_E * 2);
    unsigned short* WuT     = (unsigned short*)alloc((size_t)D_E * (2 * D_E) * 2);
    float*          wv      = (float*)alloc(6 * D_E * 4);
    float*          sd      = (float*)alloc(6 * N_V * 4);
    float*          sdg     = (float*)alloc(2 * N_V * 4);
    float*          musum   = (float*)alloc(D_E * 4);
    float*          epart   = (float*)alloc(N_V * 4);
    float*          cpart   = (float*)alloc(N_V * 4);
    int*            edges   = (int*)alloc((size_t)N_V * EDGE_CAP * 4);
    int*            deg     = (int*)alloc(N_V * 4);
    unsigned int*   bitmask = (unsigned int*)alloc((size_t)N_V * 96 * 4);

    dim3 blk(256);

    // one-time prepass
    hipMemsetAsync(W2Tx, 0, (size_t)1088 * D_E * 2, stream);   // zero pad rows
    convT_f32_bf16<<<dim3(2, D_E), blk, 0, stream>>>(W_n, W2Tx, D_E, D_E);
    convT_f32_bf16<<<dim3(2, D_E), blk, 0, stream>>>(W_nn, W2Tx + (size_t)D_E * D_E, D_E, D_E);
    convT_f32_bf16<<<dim3(4, D_E), blk, 0, stream>>>(W_u, WuT, 2 * D_E, D_E);
    conv_bf16<<<(N_V * D_E) / 256, blk, 0, stream>>>(emb_in, embb[0], N_V * D_E);
    hipMemcpyAsync(embf[0], emb_in, (size_t)N_V * D_E * 4, hipMemcpyDeviceToDevice, stream);
    hipMemsetAsync(musum, 0, D_E * sizeof(float), stream);
    build_graph<<<N_V, blk, 0, stream>>>(adj, edges, deg, bitmask);
    matvec6<<<D_E / 4, blk, 0, stream>>>(W_n, W_nn, W_g, a_src_n, a_dst_n,
                                         a_src_nn, a_dst_nn, a_src_g, a_dst_g, wv);
    conv_wv_rows<<<12, blk, 0, stream>>>(wv, W2Tx);   // rows 1024..1029

    dim3 gW2(17, N_V / 128);            // fused Wh+sd GEMM (N=1088)
    dim3 gG(8, N_V / 128);              // update GEMM (N=512)
    dim3 gNN(D_E / 64, N_V / 64);       // nn GEMM, 64x64 tile, single pass

    int cur = 0;
    for (int it = 0; it < 10; ++it) {
        int nxt = cur ^ 1;
        gemm_bf16<5><<<gW2, blk, 0, stream>>>(embb[cur], W2Tx, N_V, 1088, D_E,
                                              Whn, D_E, WhTnn, nullptr, nullptr, sd);
        nn_sm_gather<<<2 * N_V, blk, 0, stream>>>(bitmask, edges, deg, sd,
                                                  Whn, att_nn, cat_bf);
        gemm_nn64<<<gNN, blk, 0, stream>>>(att_nn, WhTnn, cat_bf);
        gemm_bf16<2><<<gG, blk, 0, stream>>>(cat_bf, WuT, N_V, D_E, 2 * D_E,
                                             embb[nxt], D_E, nullptr, embf[cur], b_u, embf[nxt]);
        cur = nxt;
    }

    // losses: mean-center -> bf16 diff-form edge loss (per-block partials)
    colsum<<<N_V / 64, blk, 0, stream>>>(embf[cur], musum);
    center_bf16<<<(N_V * D_E) / 256, blk, 0, stream>>>(embf[cur], musum, embc);
    edge_loss_c<<<N_V, blk, 0, stream>>>(edges, deg, embc, epart);
    sd_dots<2><<<N_V / 4, blk, 0, stream>>>(embb[cur], wv + 4 * D_E, sdg);
    conf_kernel<<<N_V, blk, 0, stream>>>(bitmask, sdg, sdg + N_V, cpart);

    finalize2<<<1, blk, 0, stream>>>(epart, cpart, out);
}

// Round 11
// 838.811 us; speedup vs baseline: 2.0055x; 1.0178x over previous
//
#include <hip/hip_runtime.h>
#include <math.h>

#define N_V 3072
#define D_E 512
#define EDGE_CAP 128
constexpr float LRELU_ALPHA = 0.2f;
constexpr float NEG_INF_F = -9e15f;

typedef __attribute__((ext_vector_type(8))) short bf16x8;
typedef __attribute__((ext_vector_type(4))) float f32x4;
typedef __attribute__((ext_vector_type(4))) unsigned short ushort4v;
typedef __attribute__((ext_vector_type(2))) unsigned short ushort2v;

__device__ inline unsigned short f2bf(float f) {
    union { float f; unsigned int u; } x; x.f = f;
    unsigned int r = x.u + 0x7fffu + ((x.u >> 16) & 1u);
    return (unsigned short)(r >> 16);
}
__device__ inline float bf2f(unsigned short b) {
    union { unsigned int u; float f; } x; x.u = ((unsigned int)b) << 16;
    return x.f;
}

// XCD-aware bijective swizzle of the (bx,by) plane; nwg %8==0 for all grids
// here (408/192/192-per-z).
__device__ inline void xcd_swizzle(int& bx, int& by) {
    int gx = gridDim.x, nwg = gx * gridDim.y;
    int flat = by * gx + bx;
    int q = nwg >> 3;
    int swz = (flat & 7) * q + (flat >> 3);
    bx = swz % gx; by = swz / gx;
}

// ---------------------------------------------------------------------------
// bf16 MFMA GEMM: C[M,N] = A[M,K] @ B[K,N], B given TRANSPOSED (BT[N][K]).
// Tile 128x64, BK=64, 4 waves (2x2), wave tile 64x32, 16x16x32 MFMA.
// EPI 2: relu(acc + addv + bias) -> Cf (f32, ld=N) and C0 (bf16, ldc0).
// EPI 5: three-way split by block column:
//   bn < 512          : row-major bf16 C0 (ldc0)            [Wh_n]
//   512 <= bn < 1024  : LDS-transposed bf16 C1[(col-512)][M] (coalesced)
//   bn >= 1024        : cols 1024..1029 -> fp32 Cf[(col-1024)*N_V + row]
//                       (the 6 fused s/d dot products)
// ---------------------------------------------------------------------------
template<int EPI>
__global__ __launch_bounds__(256) void gemm_bf16(
    const unsigned short* __restrict__ A,   // [M][K] bf16
    const unsigned short* __restrict__ BT,  // [N][K] bf16
    int M, int N, int K,
    unsigned short* __restrict__ C0, int ldc0,
    unsigned short* __restrict__ C1,
    const float* __restrict__ addv,
    const float* __restrict__ bias,
    float* __restrict__ Cf)
{
    constexpr int BM = 128, BN = 64, BK = 64;
    __shared__ unsigned short As[BM * BK + BN * BK];   // unified; Ts reuses it
    unsigned short* Bs = As + BM * BK;
    const int tid  = threadIdx.x;
    int bxi = blockIdx.x, byi = blockIdx.y;
    xcd_swizzle(bxi, byi);
    const int bm   = byi * BM, bn = bxi * BN;
    const int lane = tid & 63, wid = tid >> 6;
    const int wr   = wid >> 1, wc = wid & 1;
    const int lr   = lane & 15, lk = lane >> 4;

    f32x4 acc[4][2];
    #pragma unroll
    for (int i = 0; i < 4; ++i)
        #pragma unroll
        for (int j = 0; j < 2; ++j)
            acc[i][j] = (f32x4)(0.f);

    auto asp = (__attribute__((address_space(3))) unsigned short*)As;
    auto bsp = (__attribute__((address_space(3))) unsigned short*)Bs;

    for (int k0 = 0; k0 < K; k0 += BK) {
        #pragma unroll
        for (int l = 0; l < 4; ++l) {
            int li = l * 256 + tid;
            int row = li >> 3, slot = li & 7;
            int gs = slot ^ (row & 7);
            __builtin_amdgcn_global_load_lds(
                (const __attribute__((address_space(1))) void*)(A + (size_t)(bm + row) * K + k0 + gs * 8),
                (__attribute__((address_space(3))) void*)(asp + li * 8), 16, 0, 0);
        }
        #pragma unroll
        for (int l = 0; l < 2; ++l) {
            int li = l * 256 + tid;
            int row = li >> 3, slot = li & 7;
            int gs = slot ^ (row & 7);
            __builtin_amdgcn_global_load_lds(
                (const __attribute__((address_space(1))) void*)(BT + (size_t)(bn + row) * K + k0 + gs * 8),
                (__attribute__((address_space(3))) void*)(bsp + li * 8), 16, 0, 0);
        }
        __syncthreads();

        #pragma unroll
        for (int ks = 0; ks < 2; ++ks) {
            bf16x8 af[4], bfr[2];
            #pragma unroll
            for (int fm = 0; fm < 4; ++fm) {
                int row = wr * 64 + fm * 16 + lr;
                int sl = (ks * 4 + lk) ^ (row & 7);
                af[fm] = *(const bf16x8*)(As + row * BK + sl * 8);
            }
            #pragma unroll
            for (int fn = 0; fn < 2; ++fn) {
                int col = wc * 32 + fn * 16 + lr;
                int sl = (ks * 4 + lk) ^ (col & 7);
                bfr[fn] = *(const bf16x8*)(Bs + col * BK + sl * 8);
            }
            #pragma unroll
            for (int fm = 0; fm < 4; ++fm)
                #pragma unroll
                for (int fn = 0; fn < 2; ++fn)
                    acc[fm][fn] = __builtin_amdgcn_mfma_f32_16x16x32_bf16(
                        af[fm], bfr[fn], acc[fm][fn], 0, 0, 0);
        }
        __syncthreads();
    }

    if (EPI == 2) {
        #pragma unroll
        for (int fm = 0; fm < 4; ++fm) {
            #pragma unroll
            for (int fn = 0; fn < 2; ++fn) {
                int row0 = bm + wr * 64 + fm * 16 + lk * 4;
                int col  = bn + wc * 32 + fn * 16 + lr;
                f32x4 v = acc[fm][fn];
                #pragma unroll
                for (int r = 0; r < 4; ++r) {
                    float x = v[r] + addv[(size_t)(row0 + r) * N + col] + bias[col];
                    x = x > 0.f ? x : 0.f;
                    Cf[(size_t)(row0 + r) * N + col] = x;
                    C0[(size_t)(row0 + r) * ldc0 + col] = f2bf(x);
                }
            }
        }
    } else { // EPI 5
        if (bn < 512) {
            #pragma unroll
            for (int fm = 0; fm < 4; ++fm) {
                #pragma unroll
                for (int fn = 0; fn < 2; ++fn) {
                    int row0 = bm + wr * 64 + fm * 16 + lk * 4;
                    int col  = bn + wc * 32 + fn * 16 + lr;
                    #pragma unroll
                    for (int r = 0; r < 4; ++r)
                        C0[(size_t)(row0 + r) * ldc0 + col] = f2bf(acc[fm][fn][r]);
                }
            }
        } else if (bn < 1024) {
            // stage 128x64 tile transposed into LDS (Ts[64][136]), then
            // coalesced 16B stores along WhTnn rows.
            constexpr int TS = 136;
            unsigned short* Ts = As;
            #pragma unroll
            for (int fm = 0; fm < 4; ++fm) {
                #pragma unroll
                for (int fn = 0; fn < 2; ++fn) {
                    int rloc = wr * 64 + fm * 16 + lk * 4;     // local row 0..127
                    int lc   = wc * 32 + fn * 16 + lr;         // local col 0..63
                    ushort4v pk;
                    pk.x = f2bf(acc[fm][fn][0]); pk.y = f2bf(acc[fm][fn][1]);
                    pk.z = f2bf(acc[fm][fn][2]); pk.w = f2bf(acc[fm][fn][3]);
                    *(ushort4v*)(Ts + lc * TS + rloc) = pk;
                }
            }
            __syncthreads();
            for (int idx = tid; idx < 64 * 16; idx += 256) {
                int c = idx >> 4, seg = idx & 15;
                bf16x8 pk = *(const bf16x8*)(Ts + c * TS + seg * 8);
                *(bf16x8*)(C1 + (size_t)(bn - 512 + c) * M + bm + seg * 8) = pk;
            }
        } else {
            // s/d fused dot-product columns (1024..1029)
            #pragma unroll
            for (int fm = 0; fm < 4; ++fm) {
                #pragma unroll
                for (int fn = 0; fn < 2; ++fn) {
                    int row0 = bm + wr * 64 + fm * 16 + lk * 4;
                    int col  = bn + wc * 32 + fn * 16 + lr;
                    if (col >= 1024 && col < 1030) {
                        int v = col - 1024;
                        #pragma unroll
                        for (int r = 0; r < 4; ++r)
                            Cf[(size_t)v * N_V + row0 + r] = acc[fm][fn][r];
                    }
                }
            }
        }
    }
}

// ---------------------------------------------------------------------------
// nn GEMM: 128x64 tile (16 MFMA/K-step), split-K=2 via blockIdx.z,
// fp32 partials.  Grid (8, 24, 2) = 384 blocks.
// ---------------------------------------------------------------------------
__global__ __launch_bounds__(256) void gemm_nn_sk(
    const unsigned short* __restrict__ A,    // att [3072][3072] bf16
    const unsigned short* __restrict__ BT,   // WhTnn [512][3072] bf16
    float* __restrict__ Cp)                  // [2][N_V][D_E] fp32
{
    constexpr int BM = 128, BN = 64, BK = 64, K = N_V;
    __shared__ unsigned short As[BM * BK];
    __shared__ unsigned short Bs[BN * BK];
    const int tid  = threadIdx.x;
    int bxi = blockIdx.x, byi = blockIdx.y;
    xcd_swizzle(bxi, byi);
    const int bm   = byi * BM, bn = bxi * BN;
    const int kh   = K >> 1;
    const int kbeg = blockIdx.z * kh, kend = kbeg + kh;
    const int lane = tid & 63, wid = tid >> 6;
    const int wr   = wid >> 1, wc = wid & 1;
    const int lr   = lane & 15, lk = lane >> 4;

    f32x4 acc[4][2];
    #pragma unroll
    for (int i = 0; i < 4; ++i)
        #pragma unroll
        for (int j = 0; j < 2; ++j)
            acc[i][j] = (f32x4)(0.f);

    auto asp = (__attribute__((address_space(3))) unsigned short*)As;
    auto bsp = (__attribute__((address_space(3))) unsigned short*)Bs;

    for (int k0 = kbeg; k0 < kend; k0 += BK) {
        #pragma unroll
        for (int l = 0; l < 4; ++l) {
            int li = l * 256 + tid;
            int row = li >> 3, slot = li & 7;
            int gs = slot ^ (row & 7);
            __builtin_amdgcn_global_load_lds(
                (const __attribute__((address_space(1))) void*)(A + (size_t)(bm + row) * K + k0 + gs * 8),
                (__attribute__((address_space(3))) void*)(asp + li * 8), 16, 0, 0);
        }
        #pragma unroll
        for (int l = 0; l < 2; ++l) {
            int li = l * 256 + tid;
            int row = li >> 3, slot = li & 7;
            int gs = slot ^ (row & 7);
            __builtin_amdgcn_global_load_lds(
                (const __attribute__((address_space(1))) void*)(BT + (size_t)(bn + row) * K + k0 + gs * 8),
                (__attribute__((address_space(3))) void*)(bsp + li * 8), 16, 0, 0);
        }
        __syncthreads();

        #pragma unroll
        for (int ks = 0; ks < 2; ++ks) {
            bf16x8 af[4], bfr[2];
            #pragma unroll
            for (int fm = 0; fm < 4; ++fm) {
                int row = wr * 64 + fm * 16 + lr;
                int sl = (ks * 4 + lk) ^ (row & 7);
                af[fm] = *(const bf16x8*)(As + row * BK + sl * 8);
            }
            #pragma unroll
            for (int fn = 0; fn < 2; ++fn) {
                int col = wc * 32 + fn * 16 + lr;
                int sl = (ks * 4 + lk) ^ (col & 7);
                bfr[fn] = *(const bf16x8*)(Bs + col * BK + sl * 8);
            }
            #pragma unroll
            for (int fm = 0; fm < 4; ++fm)
                #pragma unroll
                for (int fn = 0; fn < 2; ++fn)
                    acc[fm][fn] = __builtin_amdgcn_mfma_f32_16x16x32_bf16(
                        af[fm], bfr[fn], acc[fm][fn], 0, 0, 0);
        }
        __syncthreads();
    }

    float* Cz = Cp + (size_t)blockIdx.z * N_V * D_E;
    #pragma unroll
    for (int fm = 0; fm < 4; ++fm) {
        #pragma unroll
        for (int fn = 0; fn < 2; ++fn) {
            int row0 = bm + wr * 64 + fm * 16 + lk * 4;
            int col  = bn + wc * 32 + fn * 16 + lr;
            #pragma unroll
            for (int r = 0; r < 4; ++r)
                Cz[(size_t)(row0 + r) * D_E + col] = acc[fm][fn][r];
        }
    }
}

// Combine 2 split-K partials + ELU -> bf16 into cat[:,512:1024].
__global__ __launch_bounds__(256) void elu_combine2(
    const float* __restrict__ p0, const float* __restrict__ p1,
    unsigned short* __restrict__ cat)
{
    int idx = blockIdx.x * 256 + threadIdx.x;   // 4-elem chunk
    float4 a = ((const float4*)p0)[idx];
    float4 b = ((const float4*)p1)[idx];
    int r = idx >> 7;
    int cc = (idx & 127) * 4;
    float v[4] = { a.x + b.x, a.y + b.y, a.z + b.z, a.w + b.w };
    ushort4v o;
    #pragma unroll
    for (int q = 0; q < 4; ++q) {
        float x = v[q];
        x = x > 0.f ? x : (expf(x) - 1.f);
        ((unsigned short*)&o)[q] = f2bf(x);
    }
    *(ushort4v*)(cat + (size_t)r * (2 * D_E) + D_E + cc) = o;
}

// ---------------------------------------------------------------------------
// WT[n][k] = bf16(W[k][n]) ; wv rows -> bf16 into W2Tx[1024+v]
// ---------------------------------------------------------------------------
__global__ __launch_bounds__(256) void convT_f32_bf16(
    const float* __restrict__ W, unsigned short* __restrict__ WT, int K, int Nw)
{
    int k = blockIdx.x * 256 + threadIdx.x;
    int n = blockIdx.y;
    if (k < K) WT[(size_t)n * K + k] = f2bf(W[(size_t)k * Nw + n]);
}

__global__ __launch_bounds__(256) void conv_bf16(
    const float* __restrict__ X, unsigned short* __restrict__ Y, int n)
{
    int i = blockIdx.x * 256 + threadIdx.x;
    if (i < n) Y[i] = f2bf(X[i]);
}

__global__ __launch_bounds__(256) void conv_wv_rows(
    const float* __restrict__ wv, unsigned short* __restrict__ W2Tx)
{
    int k = threadIdx.x + (blockIdx.x & 1) * 256;
    int v = blockIdx.x >> 1;
    W2Tx[(size_t)(1024 + v) * D_E + k] = f2bf(wv[v * D_E + k]);
}

// ---------------------------------------------------------------------------
// One-time: packed bitmask + deterministic per-row edge list.
// ---------------------------------------------------------------------------
__global__ __launch_bounds__(256) void build_graph(
    const float* __restrict__ adj, int* __restrict__ edges,
    int* __restrict__ deg, unsigned int* __restrict__ bitmask)
{
    const int i = blockIdx.x, t = threadIdx.x;
    __shared__ int cnts[256];
    unsigned int word = 0;
    int c = 0;
    if (t < 96) {
        #pragma unroll
        for (int b = 0; b < 32; ++b) {
            int j = t * 32 + b;
            if (adj[(size_t)i * N_V + j] > 0.f) { word |= (1u << b); ++c; }
        }
    }
    cnts[t] = c;
    __syncthreads();
    for (int o = 1; o < 256; o <<= 1) {
        int add = (t >= o) ? cnts[t - o] : 0;
        __syncthreads();
        cnts[t] += add;
        __syncthreads();
    }
    int base = cnts[t] - c;
    if (t < 96) {
        int k = 0;
        #pragma unroll
        for (int b = 0; b < 32; ++b) {
            if ((word >> b) & 1u) {
                int pos = base + k;
                if (pos < EDGE_CAP) edges[(size_t)i * EDGE_CAP + pos] = t * 32 + b;
                ++k;
            }
        }
        bitmask[(size_t)i * 96 + t] = word;
    }
    if (t == 0) deg[i] = cnts[255] < EDGE_CAP ? cnts[255] : EDGE_CAP;
}

// ---------------------------------------------------------------------------
// One-time: wv[0..5] = {W_n@as_n, W_n@ad_n, W_nn@as_nn, W_nn@ad_nn, W_g@as_g, W_g@ad_g}
// ---------------------------------------------------------------------------
__global__ __launch_bounds__(256) void matvec6(
    const float* __restrict__ W_n, const float* __restrict__ W_nn,
    const float* __restrict__ W_g,
    const float* __restrict__ as_n, const float* __restrict__ ad_n,
    const float* __restrict__ as_nn, const float* __restrict__ ad_nn,
    const float* __restrict__ as_g, const float* __restrict__ ad_g,
    float* __restrict__ wv)
{
    const int wave = threadIdx.x >> 6, lane = threadIdx.x & 63;
    const int r = blockIdx.x * 4 + wave;
    float a0 = 0, a1 = 0, a2 = 0, a3 = 0, a4 = 0, a5 = 0;
    #pragma unroll
    for (int k = 0; k < 8; ++k) {
        int c = lane + k * 64;
        float wn = W_n[(size_t)r * D_E + c];
        float wm = W_nn[(size_t)r * D_E + c];
        float wg = W_g[(size_t)r * D_E + c];
        a0 = fmaf(wn, as_n[c], a0);  a1 = fmaf(wn, ad_n[c], a1);
        a2 = fmaf(wm, as_nn[c], a2); a3 = fmaf(wm, ad_nn[c], a3);
        a4 = fmaf(wg, as_g[c], a4);  a5 = fmaf(wg, ad_g[c], a5);
    }
    #pragma unroll
    for (int off = 32; off; off >>= 1) {
        a0 += __shfl_down(a0, off); a1 += __shfl_down(a1, off);
        a2 += __shfl_down(a2, off); a3 += __shfl_down(a3, off);
        a4 += __shfl_down(a4, off); a5 += __shfl_down(a5, off);
    }
    if (lane == 0) {
        wv[0 * D_E + r] = a0; wv[1 * D_E + r] = a1;
        wv[2 * D_E + r] = a2; wv[3 * D_E + r] = a3;
        wv[4 * D_E + r] = a4; wv[5 * D_E + r] = a5;
    }
}

// ---------------------------------------------------------------------------
// outs[v][i] = emb_bf16[i,:] . wv[v]   (post-loop, glimpse s_g/d_g)
// ---------------------------------------------------------------------------
template<int NV>
__global__ __launch_bounds__(256) void sd_dots(
    const unsigned short* __restrict__ emb, const float* __restrict__ wv,
    float* __restrict__ outs)
{
    const int wave = threadIdx.x >> 6, lane = threadIdx.x & 63;
    const int i = blockIdx.x * 4 + wave;
    float acc[NV];
    #pragma unroll
    for (int v = 0; v < NV; ++v) acc[v] = 0.f;
    #pragma unroll
    for (int k = 0; k < 8; ++k) {
        int c = lane + k * 64;
        float x = bf2f(emb[(size_t)i * D_E + c]);
        #pragma unroll
        for (int v = 0; v < NV; ++v) acc[v] = fmaf(x, wv[v * D_E + c], acc[v]);
    }
    #pragma unroll
    for (int off = 32; off; off >>= 1)
        #pragma unroll
        for (int v = 0; v < NV; ++v) acc[v] += __shfl_down(acc[v], off);
    if (lane == 0)
        #pragma unroll
        for (int v = 0; v < NV; ++v) outs[v * N_V + i] = acc[v];
}

// ---------------------------------------------------------------------------
// Fused: blocks [0,N_V) run non-neighbor softmax (writes att bf16);
// blocks [N_V,2N_V) run the sparse neighbor gather (writes cat[:,0:512]).
// sd layout: s_n = sd, d_n = sd+N, s_nn = sd+2N, d_nn = sd+3N.
// ---------------------------------------------------------------------------
__global__ __launch_bounds__(256) void nn_sm_gather(
    const unsigned int* __restrict__ bitmask,
    const int* __restrict__ edges, const int* __restrict__ deg,
    const float* __restrict__ sd,
    const unsigned short* __restrict__ Whn,
    unsigned short* __restrict__ att, unsigned short* __restrict__ cat)
{
    const int t = threadIdx.x;
    __shared__ float red[256];
    if (blockIdx.x < N_V) {
        const int i = blockIdx.x;
        const float* s = sd + 2 * N_V;
        const float* dvec = sd + 3 * N_V;
        __shared__ unsigned int mrow[96];
        if (t < 96) mrow[t] = bitmask[(size_t)i * 96 + t];
        __syncthreads();
        const float si = s[i];
        const float4* dv4 = (const float4*)dvec;
        float e[3][4];
        float mloc = -3.4e38f;
        #pragma unroll
        for (int l = 0; l < 3; ++l) {
            int jv = t + l * 256;
            float4 d = dv4[jv];
            int j0 = jv * 4;
            unsigned int w = mrow[j0 >> 5];
            #pragma unroll
            for (int c = 0; c < 4; ++c) {
                int j = j0 + c;
                bool keep = (((w >> (j & 31)) & 1u) == 0u) && (j != i);
                float x = si + ((const float*)&d)[c];
                x = x > 0.f ? x : LRELU_ALPHA * x;
                e[l][c] = keep ? x : NEG_INF_F;
                mloc = fmaxf(mloc, e[l][c]);
            }
        }
        red[t] = mloc; __syncthreads();
        for (int o = 128; o; o >>= 1) {
            if (t < o) red[t] = fmaxf(red[t], red[t + o]);
            __syncthreads();
        }
        float m = red[0]; __syncthreads();
        float zloc = 0.f;
        #pragma unroll
        for (int l = 0; l < 3; ++l)
            #pragma unroll
            for (int c = 0; c < 4; ++c) { e[l][c] = expf(e[l][c] - m); zloc += e[l][c]; }
        red[t] = zloc; __syncthreads();
        for (int o = 128; o; o >>= 1) {
            if (t < o) red[t] += red[t + o];
            __syncthreads();
        }
        const float zinv = 1.f / red[0];
        #pragma unroll
        for (int l = 0; l < 3; ++l) {
            int jv = t + l * 256;
            ushort4v p;
            p.x = f2bf(e[l][0] * zinv); p.y = f2bf(e[l][1] * zinv);
            p.z = f2bf(e[l][2] * zinv); p.w = f2bf(e[l][3] * zinv);
            *(ushort4v*)(att + (size_t)i * N_V + (size_t)jv * 4) = p;
        }
    } else {
        const int i = blockIdx.x - N_V;
        const float* s = sd;
        const float* dvec = sd + N_V;
        const int cnt = deg[i];
        __shared__ float p[EDGE_CAP];
        __shared__ int lst[EDGE_CAP];
        float ev = -3.4e38f;
        if (t < cnt) {
            int j = edges[(size_t)i * EDGE_CAP + t];
            lst[t] = j;
            float x = s[i] + dvec[j];
            x = x > 0.f ? x : LRELU_ALPHA * x;
            p[t] = x;
            ev = x;
        }
        red[t] = ev; __syncthreads();
        for (int o = 128; o; o >>= 1) {
            if (t < o) red[t] = fmaxf(red[t], red[t + o]);
            __syncthreads();
        }
        float m = red[0]; __syncthreads();
        float pe = 0.f;
        if (t < cnt) { pe = expf(p[t] - m); p[t] = pe; }
        red[t] = pe; __syncthreads();
        for (int o = 128; o; o >>= 1) {
            if (t < o) red[t] += red[t + o];
            __syncthreads();
        }
        const float zinv = 1.f / red[0];
        float a0 = 0.f, a1 = 0.f;
        for (int e = 0; e < cnt; ++e) {
            int j = lst[e];
            float w = p[e] * zinv;
            ushort2v h = *(const ushort2v*)(Whn + (size_t)j * D_E + t * 2);
            a0 = fmaf(w, bf2f(h.x), a0);
            a1 = fmaf(w, bf2f(h.y), a1);
        }
        a0 = a0 > 0.f ? a0 : (expf(a0) - 1.f);
        a1 = a1 > 0.f ? a1 : (expf(a1) - 1.f);
        ushort2v o2; o2.x = f2bf(a0); o2.y = f2bf(a1);
        *(ushort2v*)(cat + (size_t)i * (2 * D_E) + t * 2) = o2;
    }
}

// ---------------------------------------------------------------------------
// Column sums of fp32 emb (for mean-centering).
// ---------------------------------------------------------------------------
__global__ __launch_bounds__(256) void colsum(
    const float* __restrict__ emb, float* __restrict__ musum)
{
    const int b = blockIdx.x, t = threadIdx.x;
    float s0 = 0.f, s1 = 0.f;
    for (int r = 0; r < 64; ++r) {
        const float* row = emb + (size_t)(b * 64 + r) * D_E;
        s0 += row[t];
        s1 += row[t + 256];
    }
    atomicAdd(&musum[t], s0);
    atomicAdd(&musum[t + 256], s1);
}

// embc[i][c] = bf16(emb[i][c] - musum[c]/N)
__global__ __launch_bounds__(256) void center_bf16(
    const float* __restrict__ emb, const float* __restrict__ musum,
    unsigned short* __restrict__ embc)
{
    int i = blockIdx.x * 256 + threadIdx.x;
    int c = i & (D_E - 1);
    embc[i] = f2bf(emb[i] - musum[c] * (1.f / N_V));
}

// ---------------------------------------------------------------------------
// Edge loss on centered bf16 via diff-form; per-block partial to epart[i].
// ---------------------------------------------------------------------------
__global__ __launch_bounds__(256) void edge_loss_c(
    const int* __restrict__ edges, const int* __restrict__ deg,
    const unsigned short* __restrict__ embc, float* __restrict__ epart)
{
    __shared__ unsigned short rowi[D_E];
    __shared__ float gsum[16];
    const int i = blockIdx.x, t = threadIdx.x;
    if (t < 64) ((bf16x8*)rowi)[t] = ((const bf16x8*)(embc + (size_t)i * D_E))[t];
    __syncthreads();
    const int g = t >> 4, l = t & 15;
    const int cnt = deg[i];
    float sum = 0.f;
    for (int e = g; e < cnt; e += 16) {
        int j = edges[(size_t)i * EDGE_CAP + e];
        float d2 = 0.f;
        #pragma unroll
        for (int q = 0; q < 4; ++q) {
            int off = q * 128 + l * 8;
            bf16x8 a = *(const bf16x8*)(rowi + off);
            bf16x8 b = *(const bf16x8*)(embc + (size_t)j * D_E + off);
            #pragma unroll
            for (int k = 0; k < 8; ++k) {
                float df = bf2f(((unsigned short*)&a)[k]) -
                           bf2f(((unsigned short*)&b)[k]);
                d2 = fmaf(df, df, d2);
            }
        }
        #pragma unroll
        for (int msk = 1; msk < 16; msk <<= 1) d2 += __shfl_xor(d2, msk);
        if (l == 0) sum += sqrtf(fmaxf(d2, 1e-12f));
    }
    if (l == 0) gsum[g] = sum;
    __syncthreads();
    if (t == 0) {
        float tot = 0.f;
        #pragma unroll
        for (int k = 0; k < 16; ++k) tot += gsum[k];
        epart[i] = tot;
    }
}

// ---------------------------------------------------------------------------
// Glimpse confidence via EDGE LIST: Z_i = sum over neighbors only (~32 terms).
// One wave per row; cpart[i] = log(1/Z_i + 1e-8).
// ---------------------------------------------------------------------------
__global__ __launch_bounds__(256) void conf_edge(
    const int* __restrict__ edges, const int* __restrict__ deg,
    const float* __restrict__ s, const float* __restrict__ dvec,
    float* __restrict__ cpart)
{
    const int wave = threadIdx.x >> 6, lane = threadIdx.x & 63;
    const int i = blockIdx.x * 4 + wave;
    const int cnt = deg[i];
    const float si = s[i];
    float x0 = -3.4e38f, x1 = -3.4e38f;
    if (lane < cnt) {
        int j = edges[(size_t)i * EDGE_CAP + lane];
        float x = si + dvec[j];
        x0 = x > 0.f ? x : LRELU_ALPHA * x;
    }
    if (lane + 64 < cnt) {
        int j = edges[(size_t)i * EDGE_CAP + lane + 64];
        float x = si + dvec[j];
        x1 = x > 0.f ? x : LRELU_ALPHA * x;
    }
    float m = fmaxf(x0, x1);
    #pragma unroll
    for (int msk = 32; msk; msk >>= 1) m = fmaxf(m, __shfl_xor(m, msk));
    float z = (lane < cnt ? expf(x0 - m) : 0.f) +
              (lane + 64 < cnt ? expf(x1 - m) : 0.f);
    #pragma unroll
    for (int msk = 32; msk; msk >>= 1) z += __shfl_xor(z, msk);
    if (lane == 0) cpart[i] = logf(1.f / z + 1e-8f);
}

// Final deterministic reduction of both partial arrays + output write.
__global__ __launch_bounds__(256) void finalize2(
    const float* __restrict__ epart, const float* __restrict__ cpart,
    float* __restrict__ out)
{
    const int t = threadIdx.x;
    float e = 0.f, c = 0.f;
    #pragma unroll
    for (int k = 0; k < 12; ++k) {
        e += epart[t + k * 256];
        c += cpart[t + k * 256];
    }
    __shared__ float re[256], rc[256];
    re[t] = e; rc[t] = c;
    __syncthreads();
    for (int o = 128; o; o >>= 1) {
        if (t < o) { re[t] += re[t + o]; rc[t] += rc[t + o]; }
        __syncthreads();
    }
    if (t == 0) {
        float loss = -re[0];
        out[0] = fmaxf(loss + 400.f, 0.f);
        out[1] = loss;
        out[2] = rc[0] / (float)N_V - logf(1e-8f);
    }
}

// ---------------------------------------------------------------------------
extern "C" void kernel_launch(void* const* d_in, const int* in_sizes, int n_in,
                              void* d_out, int out_size, void* d_ws, size_t ws_size,
                              hipStream_t stream) {
    const float* emb_in   = (const float*)d_in[0];
    const float* adj      = (const float*)d_in[1];
    const float* W_n      = (const float*)d_in[2];
    const float* a_src_n  = (const float*)d_in[3];
    const float* a_dst_n  = (const float*)d_in[4];
    const float* W_nn     = (const float*)d_in[5];
    const float* a_src_nn = (const float*)d_in[6];
    const float* a_dst_nn = (const float*)d_in[7];
    const float* W_u      = (const float*)d_in[8];
    const float* b_u      = (const float*)d_in[9];
    const float* W_g      = (const float*)d_in[10];
    const float* a_src_g  = (const float*)d_in[11];
    const float* a_dst_g  = (const float*)d_in[12];
    float* out = (float*)d_out;

    char* p = (char*)d_ws;
    auto alloc = [&](size_t bytes) { char* r = p; p += (bytes + 255) & ~(size_t)255; return r; };

    unsigned short* att_nn  = (unsigned short*)alloc((size_t)N_V * N_V * 2);
    float*          Cp      = (float*)alloc((size_t)2 * N_V * D_E * 4);
    unsigned short* Whn     = (unsigned short*)alloc((size_t)N_V * D_E * 2);
    unsigned short* WhTnn   = (unsigned short*)alloc((size_t)D_E * N_V * 2);
    unsigned short* cat_bf  = (unsigned short*)alloc((size_t)N_V * 2 * D_E * 2);
    float*          embf[2] = { (float*)alloc((size_t)N_V * D_E * 4),
                                (float*)alloc((size_t)N_V * D_E * 4) };
    unsigned short* embb[2] = { (unsigned short*)alloc((size_t)N_V * D_E * 2),
                                (unsigned short*)alloc((size_t)N_V * D_E * 2) };
    unsigned short* embc    = (unsigned short*)alloc((size_t)N_V * D_E * 2);
    unsigned short* W2Tx    = (unsigned short*)alloc((size_t)1088 * D_E * 2);
    unsigned short* WuT     = (unsigned short*)alloc((size_t)D_E * (2 * D_E) * 2);
    float*          wv      = (float*)alloc(6 * D_E * 4);
    float*          sd      = (float*)alloc(6 * N_V * 4);
    float*          sdg     = (float*)alloc(2 * N_V * 4);
    float*          musum   = (float*)alloc(D_E * 4);
    float*          epart   = (float*)alloc(N_V * 4);
    float*          cpart   = (float*)alloc(N_V * 4);
    int*            edges   = (int*)alloc((size_t)N_V * EDGE_CAP * 4);
    int*            deg     = (int*)alloc(N_V * 4);
    unsigned int*   bitmask = (unsigned int*)alloc((size_t)N_V * 96 * 4);

    dim3 blk(256);

    // one-time prepass
    hipMemsetAsync(W2Tx, 0, (size_t)1088 * D_E * 2, stream);   // zero pad rows
    convT_f32_bf16<<<dim3(2, D_E), blk, 0, stream>>>(W_n, W2Tx, D_E, D_E);
    convT_f32_bf16<<<dim3(2, D_E), blk, 0, stream>>>(W_nn, W2Tx + (size_t)D_E * D_E, D_E, D_E);
    convT_f32_bf16<<<dim3(4, D_E), blk, 0, stream>>>(W_u, WuT, 2 * D_E, D_E);
    conv_bf16<<<(N_V * D_E) / 256, blk, 0, stream>>>(emb_in, embb[0], N_V * D_E);
    hipMemcpyAsync(embf[0], emb_in, (size_t)N_V * D_E * 4, hipMemcpyDeviceToDevice, stream);
    hipMemsetAsync(musum, 0, D_E * sizeof(float), stream);
    build_graph<<<N_V, blk, 0, stream>>>(adj, edges, deg, bitmask);
    matvec6<<<D_E / 4, blk, 0, stream>>>(W_n, W_nn, W_g, a_src_n, a_dst_n,
                                         a_src_nn, a_dst_nn, a_src_g, a_dst_g, wv);
    conv_wv_rows<<<12, blk, 0, stream>>>(wv, W2Tx);   // rows 1024..1029

    dim3 gW2(17, N_V / 128);            // fused Wh+sd GEMM (N=1088)
    dim3 gG(8, N_V / 128);              // update GEMM (N=512)
    dim3 gNN(8, N_V / 128, 2);          // nn GEMM, 128x64 tile, split-K2

    int cur = 0;
    for (int it = 0; it < 10; ++it) {
        int nxt = cur ^ 1;
        gemm_bf16<5><<<gW2, blk, 0, stream>>>(embb[cur], W2Tx, N_V, 1088, D_E,
                                              Whn, D_E, WhTnn, nullptr, nullptr, sd);
        nn_sm_gather<<<2 * N_V, blk, 0, stream>>>(bitmask, edges, deg, sd,
                                                  Whn, att_nn, cat_bf);
        gemm_nn_sk<<<gNN, blk, 0, stream>>>(att_nn, WhTnn, Cp);
        elu_combine2<<<(N_V * D_E) / (4 * 256), blk, 0, stream>>>(
            Cp, Cp + (size_t)N_V * D_E, cat_bf);
        gemm_bf16<2><<<gG, blk, 0, stream>>>(cat_bf, WuT, N_V, D_E, 2 * D_E,
                                             embb[nxt], D_E, nullptr, embf[cur], b_u, embf[nxt]);
        cur = nxt;
    }

    // losses: mean-center -> bf16 diff-form edge loss (per-block partials)
    colsum<<<N_V / 64, blk, 0, stream>>>(embf[cur], musum);
    center_bf16<<<(N_V * D_E) / 256, blk, 0, stream>>>(embf[cur], musum, embc);
    edge_loss_c<<<N_V, blk, 0, stream>>>(edges, deg, embc, epart);
    sd_dots<2><<<N_V / 4, blk, 0, stream>>>(embb[cur], wv + 4 * D_E, sdg);
    conf_edge<<<N_V / 4, blk, 0, stream>>>(edges, deg, sdg, sdg + N_V, cpart);

    finalize2<<<1, blk, 0, stream>>>(epart, cpart, out);
}